// Round 1
// 436.085 us; speedup vs baseline: 1.3406x; 1.3406x over previous
//
#include <hip/hip_runtime.h>
#include <hip/hip_bf16.h>

// MLA forward. Storage fp32 in/out; internal pipeline bf16 MFMA, fp32 accum.
// R1 changes vs baseline (583us):
//  - attn_kernel: bijective XCD swizzle so each XCD owns 4 (b,h) -> K/V fits
//    its private L2 (FETCH was 260MB = 8x over-fetch from round-robin).
//  - mfma_gemm: global_load_lds (width 16) staging into linear LDS (m97
//    structure, 517->874 TF prior), replacing reg-staged padded LDS.
//  - fused projections: [ckv|cq|kr] one N=1536 GEMM, [uq|qr] one N=2048 GEMM
//    (multi-segment epilogue) -> full-chip grids, h/cq read once.
#define B_   2
#define S_   2048
#define E_   2048
#define H_   16
#define DH_  128
#define DR_  32
#define SP_  96
#define C_   512
#define M_   (B_ * S_)   // 4096 rows

#define LOG2E 1.4426950408889634f

typedef __attribute__((ext_vector_type(8))) short short8;
typedef __attribute__((ext_vector_type(4))) float floatx4;

__device__ __forceinline__ float bfu(unsigned short u) {
  return __uint_as_float((unsigned)u << 16);
}
__device__ __forceinline__ unsigned short f2bf(float f) {
  unsigned u = __float_as_uint(f);
  return (unsigned short)((u + 0x7fff + ((u >> 16) & 1)) >> 16);  // RNE
}

// async global->LDS, 16B per lane. LDS dest must be wave-uniform base;
// HW writes lds_base + lane*16. Global src is per-lane.
__device__ __forceinline__ void gload16(const void* g, void* l) {
  __builtin_amdgcn_global_load_lds(
      (const __attribute__((address_space(1))) void*)g,
      (__attribute__((address_space(3))) void*)l, 16, 0, 0);
}

// ---------- fp32 -> bf16 bulk convert (for h) ----------
__global__ __launch_bounds__(256) void f2bf_kernel(
    const float* __restrict__ src, unsigned short* __restrict__ dst) {
  size_t i = ((size_t)blockIdx.x * 256 + threadIdx.x) * 4;
  float4 v = *(const float4*)(src + i);
  ushort4 w;
  w.x = f2bf(v.x); w.y = f2bf(v.y); w.z = f2bf(v.z); w.w = f2bf(v.w);
  *(ushort4*)(dst + i) = w;
}

// ---------- W[K][N] fp32 -> Wt[N][K] bf16 ----------
__global__ __launch_bounds__(256) void transpose_w_kernel(
    const float* __restrict__ W, unsigned short* __restrict__ Wt, int K, int N) {
  __shared__ unsigned short T[32][33];
  int n0 = blockIdx.x * 32, k0 = blockIdx.y * 32;
  int t = threadIdx.x, lane = t & 31, grp = t >> 5;
#pragma unroll
  for (int p = 0; p < 4; p++) {
    int k = p * 8 + grp;
    T[lane][k] = f2bf(W[(size_t)(k0 + k) * N + n0 + lane]);
  }
  __syncthreads();
#pragma unroll
  for (int p = 0; p < 4; p++) {
    int n = p * 8 + grp;
    Wt[(size_t)(n0 + n) * K + k0 + lane] = T[n][lane];
  }
}

// ---------- bf16 MFMA GEMM, multi-segment epilogue ----------
// C = A(MxK) @ Wt(NxK)^T. Each 128-col block selects the segment covering its
// bn; within a segment: n_local = n - nstart,
//   dst col = obase + (n_local/chunk)*gstride + n_local%chunk (head remap),
//   dst idx = m*orow + col. biasM (row-indexed bias) used by the swapped-
// operand V^T projection. Unused segments: nstart = INT_MAX.
struct Seg {
  float* outF;
  unsigned short* outB;
  const float* bias;    // indexed by n_local
  const float* biasM;   // indexed by m (overrides bias)
  int orow, chunk, gstride, obase, nstart;
};

__global__ __launch_bounds__(256) void mfma_gemm(
    const unsigned short* __restrict__ A, const unsigned short* __restrict__ Wt,
    Seg s0, Seg s1, Seg s2, int K) {
  __shared__ unsigned short As[128 * 32];  // linear: global_load_lds dest
  __shared__ unsigned short Bs[128 * 32];
  int tid = threadIdx.x;
  int lane = tid & 63, wave = tid >> 6;
  int l16 = lane & 15, quad = lane >> 4;
  int bm = blockIdx.y * 128, bn = blockIdx.x * 128;
  int wm = (wave & 1) * 64, wn = (wave >> 1) * 64;

  floatx4 acc[4][4];
#pragma unroll
  for (int mt = 0; mt < 4; mt++)
#pragma unroll
    for (int nt = 0; nt < 4; nt++) acc[mt][nt] = (floatx4){0.f, 0.f, 0.f, 0.f};

  // staging: 8 chunks of 1KB per operand (16 rows x 64B each); wave w owns
  // chunks 2w, 2w+1. Within a chunk: lane -> row lane>>2, 16B slot lane&3.
  int c0 = wave * 2, c1 = c0 + 1;
  int srow = lane >> 2, scol = (lane & 3) * 8;
  const unsigned short* Ag0 = A + (size_t)(bm + c0 * 16 + srow) * K + scol;
  const unsigned short* Ag1 = A + (size_t)(bm + c1 * 16 + srow) * K + scol;
  const unsigned short* Bg0 = Wt + (size_t)(bn + c0 * 16 + srow) * K + scol;
  const unsigned short* Bg1 = Wt + (size_t)(bn + c1 * 16 + srow) * K + scol;
  unsigned short* Al0 = &As[c0 * 512];
  unsigned short* Al1 = &As[c1 * 512];
  unsigned short* Bl0 = &Bs[c0 * 512];
  unsigned short* Bl1 = &Bs[c1 * 512];

  for (int k0 = 0; k0 < K; k0 += 32) {
    gload16(Ag0 + k0, Al0);
    gload16(Ag1 + k0, Al1);
    gload16(Bg0 + k0, Bl0);
    gload16(Bg1 + k0, Bl1);
    __syncthreads();  // compiler drains vmcnt here
    short8 af[4], bfr[4];
#pragma unroll
    for (int mt = 0; mt < 4; mt++)
      af[mt] = *(const short8*)&As[(wm + mt * 16 + l16) * 32 + quad * 8];
#pragma unroll
    for (int nt = 0; nt < 4; nt++)
      bfr[nt] = *(const short8*)&Bs[(wn + nt * 16 + l16) * 32 + quad * 8];
#pragma unroll
    for (int mt = 0; mt < 4; mt++)
#pragma unroll
      for (int nt = 0; nt < 4; nt++)
        acc[mt][nt] = __builtin_amdgcn_mfma_f32_16x16x32_bf16(
            af[mt], bfr[nt], acc[mt][nt], 0, 0, 0);
    __syncthreads();
  }

  Seg sg = (bn >= s2.nstart) ? s2 : ((bn >= s1.nstart) ? s1 : s0);

  // C/D layout: D[row=quad*4+r][col=l16]
#pragma unroll
  for (int mt = 0; mt < 4; mt++) {
    int m0 = bm + wm + mt * 16 + quad * 4;
    float bm4[4] = {0.f, 0.f, 0.f, 0.f};
    if (sg.biasM) {
#pragma unroll
      for (int r = 0; r < 4; r++) bm4[r] = sg.biasM[m0 + r];
    }
#pragma unroll
    for (int nt = 0; nt < 4; nt++) {
      int n = bn + wn + nt * 16 + l16;
      int nl = n - sg.nstart;
      float bv = sg.biasM ? 0.f : sg.bias[nl];
      int ncol = sg.obase + (nl / sg.chunk) * sg.gstride + (nl % sg.chunk);
#pragma unroll
      for (int r = 0; r < 4; r++) {
        float val = acc[mt][nt][r] + (sg.biasM ? bm4[r] : bv);
        size_t idx = (size_t)(m0 + r) * sg.orow + ncol;
        if (sg.outF) sg.outF[idx] = val;
        if (sg.outB) sg.outB[idx] = f2bf(val);
      }
    }
  }
}

// ---------- RoPE on bf16 q/k; fp32 k_rot to d_out ----------
__global__ __launch_bounds__(256) void rope_kernel(
    unsigned short* __restrict__ qf, unsigned short* __restrict__ kf,
    float* __restrict__ krot_out) {
  int idx = blockIdx.x * 256 + threadIdx.x;
  int j  = idx & 7;
  int h  = (idx >> 3) & (H_ - 1);
  int bs = idx >> 7;
  if (bs >= M_) return;
  int s = bs & (S_ - 1);
  float t = (float)s / 40.0f;
  float ang = t * exp2f(-1.6609640474436813f * (float)j);  // 10000^(-j/8)
  float c = cosf(ang), sn = sinf(ang);

  size_t base = (size_t)bs * 2048 + h * 128 + 96;
  float x0 = bfu(qf[base + j]), x1 = bfu(qf[base + j + 8]);
  qf[base + j]     = f2bf(x0 * c - x1 * sn);
  qf[base + j + 8] = f2bf(x1 * c + x0 * sn);

  float y0 = bfu(kf[base + j]), y1 = bfu(kf[base + j + 8]);
  float r0 = y0 * c - y1 * sn;
  float r1 = y1 * c + y0 * sn;
  kf[base + j]     = f2bf(r0);
  kf[base + j + 8] = f2bf(r1);

  size_t ko = (size_t)bs * (H_ * DR_) + h * DR_;
  krot_out[ko + j]      = r0;
  krot_out[ko + j + 8]  = r1;
  krot_out[ko + 16 + j] = bfu(kf[base + 16 + j]);
  krot_out[ko + 24 + j] = bfu(kf[base + 24 + j]);
}

// ---------- flash attention v2: paired q-tiles, no running max ----------
// vt layout: [h*128+d][b*2048+s]  (row-major, orow 4096)
// XCD swizzle: grid=512; HW dispatches blockIdx round-robin over 8 XCDs.
// Remap so XCD x owns bh in [4x, 4x+4): its K/V working set = 4MB = its L2.
#define KST 136
#define VST 40
#define PST 40
__global__ __launch_bounds__(256) void attn_kernel(
    const unsigned short* __restrict__ qf, const unsigned short* __restrict__ kf,
    const unsigned short* __restrict__ vt, unsigned short* __restrict__ ao) {
  __shared__ unsigned short Ks[32 * KST];
  __shared__ unsigned short Vs[128 * VST];
  __shared__ unsigned short Ps[4][16 * PST];

  int bid0 = blockIdx.x;
  int xcd  = bid0 & 7;          // HW XCD of this block (round-robin)
  int idx  = bid0 >> 3;         // 0..63 within XCD
  int bh   = xcd * 4 + (idx >> 4);  // 4 bh per XCD
  int jp   = idx & 15;          // pair index: q-tiles jp and 31-jp
  int h    = bh & 15;
  int b    = bh >> 4;

  int tid  = threadIdx.x;
  int wave = tid >> 6;
  int lane = tid & 63;
  int l16  = lane & 15;
  int quad = lane >> 4;

  // staging maps
  int srow  = tid >> 3;          // K rows 0..31
  int sd0   = (tid & 7) * 16;    // K d-offset
  int vrow  = tid >> 1;          // Vt rows 0..127 (d)
  int vhalf = (tid & 1) * 16;    // Vt k-offset

  // fold 1/sqrt(128) * log2(e) into Q so p = exp2(s) directly
  const float qscale = 0.08838834764831845f * LOG2E;

  for (int half = 0; half < 2; half++) {
    int jj = half ? (31 - jp) : jp;
    int q0 = jj << 6;

    int qrow = q0 + wave * 16 + l16;
    const unsigned short* qbase =
        qf + ((size_t)(b * S_ + qrow)) * 2048 + h * 128 + quad * 8;
    short8 qfrag[4];
#pragma unroll
    for (int c = 0; c < 4; c++) {
      union { short8 v; unsigned short u[8]; } in, outv;
      in.v = *(const short8*)(qbase + c * 32);
#pragma unroll
      for (int i = 0; i < 8; i++) outv.u[i] = f2bf(bfu(in.u[i]) * qscale);
      qfrag[c] = outv.v;
    }

    floatx4 Oacc[8];
#pragma unroll
    for (int dt = 0; dt < 8; dt++) Oacc[dt] = (floatx4){0.f, 0.f, 0.f, 0.f};
    float lpart[4] = {0.f, 0.f, 0.f, 0.f};

    int qg_lo = q0 + wave * 16;    // min q row of this wave
    int qg_hi = qg_lo + 15;
    int nkt = (q0 >> 5) + 2;

    for (int kt = 0; kt < nkt; kt++) {
      int kt0 = kt << 5;
      {  // stage K tile [32 k][128 d]
        const unsigned short* src =
            kf + ((size_t)(b * S_ + kt0 + srow)) * 2048 + h * 128 + sd0;
        unsigned short* dst = &Ks[srow * KST + sd0];
        *(short8*)dst       = *(const short8*)src;
        *(short8*)(dst + 8) = *(const short8*)(src + 8);
      }
      {  // stage V^T tile [128 d][32 k] -- straight copies from vt
        const unsigned short* src =
            vt + ((size_t)(h * 128 + vrow)) * 4096 + b * 2048 + kt0 + vhalf;
        unsigned short* dst = &Vs[vrow * VST + vhalf];
        *(short8*)dst       = *(const short8*)src;
        *(short8*)(dst + 8) = *(const short8*)(src + 8);
      }
      __syncthreads();

      if (kt0 <= qg_hi) {  // wave has at least one unmasked score
        bool diag = (kt0 + 31 > qg_lo);

        floatx4 s[2];
#pragma unroll
        for (int nt = 0; nt < 2; nt++) {
          floatx4 a2 = {0.f, 0.f, 0.f, 0.f};
#pragma unroll
          for (int c = 0; c < 4; c++) {
            short8 kfrag = *(const short8*)&Ks[(nt * 16 + l16) * KST + c * 32 + quad * 8];
            a2 = __builtin_amdgcn_mfma_f32_16x16x32_bf16(qfrag[c], kfrag, a2, 0, 0, 0);
          }
          s[nt] = a2;
        }

        unsigned short* P = Ps[wave];
#pragma unroll
        for (int r = 0; r < 4; r++) {
          float p0 = exp2f(fminf(s[0][r], 80.f));
          float p1 = exp2f(fminf(s[1][r], 80.f));
          if (diag) {
            int q_r = qg_lo + quad * 4 + r;
            if (kt0 + l16 > q_r)      p0 = 0.f;
            if (kt0 + 16 + l16 > q_r) p1 = 0.f;
          }
          P[(quad * 4 + r) * PST + l16]      = f2bf(p0);
          P[(quad * 4 + r) * PST + 16 + l16] = f2bf(p1);
          lpart[r] += p0 + p1;
        }

        short8 pfrag = *(const short8*)&P[l16 * PST + quad * 8];
#pragma unroll
        for (int dt = 0; dt < 8; dt++) {
          short8 vfrag = *(const short8*)&Vs[(dt * 16 + l16) * VST + quad * 8];
          Oacc[dt] = __builtin_amdgcn_mfma_f32_16x16x32_bf16(pfrag, vfrag, Oacc[dt], 0, 0, 0);
        }
      }
      __syncthreads();
    }

    // epilogue: one l-reduction per q-tile
    float linv[4];
#pragma unroll
    for (int r = 0; r < 4; r++) {
      float ls = lpart[r];
#pragma unroll
      for (int sh = 1; sh < 16; sh <<= 1) ls += __shfl_xor(ls, sh);
      linv[r] = 1.0f / ls;
    }
    int qg = q0 + wave * 16 + quad * 4;
#pragma unroll
    for (int r = 0; r < 4; r++) {
      unsigned short* dst = ao + ((size_t)(b * S_ + qg + r)) * 2048 + h * 128 + l16;
#pragma unroll
      for (int dt = 0; dt < 8; dt++) dst[dt * 16] = f2bf(Oacc[dt][r] * linv[r]);
    }
  }
}

static inline Seg mkseg(float* oF, unsigned short* oB, const float* bias,
                        const float* biasM, int orow, int chunk, int gstride,
                        int obase, int nstart) {
  Seg s;
  s.outF = oF; s.outB = oB; s.bias = bias; s.biasM = biasM;
  s.orow = orow; s.chunk = chunk; s.gstride = gstride;
  s.obase = obase; s.nstart = nstart;
  return s;
}
static inline Seg segnone() {
  return mkseg(nullptr, nullptr, nullptr, nullptr, 1, 1, 1, 0, 0x7fffffff);
}

extern "C" void kernel_launch(void* const* d_in, const int* in_sizes, int n_in,
                              void* d_out, int out_size, void* d_ws, size_t ws_size,
                              hipStream_t stream) {
  const float* h     = (const float*)d_in[0];
  const float* W_dkv = (const float*)d_in[1];
  const float* b_dkv = (const float*)d_in[2];
  const float* W_dq  = (const float*)d_in[3];
  const float* b_dq  = (const float*)d_in[4];
  const float* W_uk  = (const float*)d_in[5];
  const float* b_uk  = (const float*)d_in[6];
  const float* W_uv  = (const float*)d_in[7];
  const float* b_uv  = (const float*)d_in[8];
  const float* W_uq  = (const float*)d_in[9];
  const float* b_uq  = (const float*)d_in[10];
  const float* W_qr  = (const float*)d_in[11];
  const float* b_qr  = (const float*)d_in[12];
  const float* W_kr  = (const float*)d_in[13];
  const float* b_kr  = (const float*)d_in[14];
  const float* W_out = (const float*)d_in[15];
  const float* b_out = (const float*)d_in[16];

  float* out      = (float*)d_out;
  float* out_ckv  = out + (size_t)M_ * E_;
  float* out_krot = out_ckv + (size_t)M_ * C_;

  unsigned short* w16 = (unsigned short*)d_ws;
  unsigned short* h_bf   = w16;                 //  8,388,608
  unsigned short* q_bf   = w16 + 8388608;       //  8,388,608
  unsigned short* k_bf   = w16 + 16777216;      //  8,388,608
  unsigned short* vt_bf  = w16 + 25165824;      //  8,388,608  (V^T)
  unsigned short* ao_bf  = w16 + 33554432;      //  8,388,608
  unsigned short* ckv_bf = w16 + 41943040;      //  2,097,152
  unsigned short* cq_bf  = w16 + 44040192;      //  2,097,152
  // fused weight 1: rows [0,512)=W_dkv^T, [512,1024)=W_dq^T, [1024,1536)=W_kr^T
  unsigned short* Wt_dkv = w16 + 46137344;      //  1,048,576
  unsigned short* Wt_dq  = w16 + 47185920;      //  1,048,576 (= WtF1 + 512*2048)
  unsigned short* Wt_kr  = w16 + 48234496;      //  1,048,576 (= WtF1 + 1024*2048)
  unsigned short* Wt_uk  = w16 + 49283072;      //    786,432
  unsigned short* Wt_uv  = w16 + 50069504;      //  1,048,576
  // fused weight 2: rows [0,1536)=W_uq^T, [1536,2048)=W_qr^T
  unsigned short* Wt_uq  = w16 + 51118080;      //    786,432
  unsigned short* Wt_qr  = w16 + 51904512;      //    262,144 (= WtF2 + 1536*512)
  unsigned short* Wt_out = w16 + 52166656;      //  4,194,304

  dim3 blk(256);

  // conversions / transposes
  f2bf_kernel<<<8192, blk, 0, stream>>>(h, h_bf);
  transpose_w_kernel<<<dim3(C_ / 32, E_ / 32), blk, 0, stream>>>(W_dkv, Wt_dkv, E_, C_);
  transpose_w_kernel<<<dim3(C_ / 32, E_ / 32), blk, 0, stream>>>(W_dq, Wt_dq, E_, C_);
  transpose_w_kernel<<<dim3((H_ * DR_) / 32, E_ / 32), blk, 0, stream>>>(W_kr, Wt_kr, E_, H_ * DR_);
  transpose_w_kernel<<<dim3((H_ * SP_) / 32, C_ / 32), blk, 0, stream>>>(W_uk, Wt_uk, C_, H_ * SP_);
  transpose_w_kernel<<<dim3((H_ * DH_) / 32, C_ / 32), blk, 0, stream>>>(W_uv, Wt_uv, C_, H_ * DH_);
  transpose_w_kernel<<<dim3((H_ * SP_) / 32, C_ / 32), blk, 0, stream>>>(W_uq, Wt_uq, C_, H_ * SP_);
  transpose_w_kernel<<<dim3((H_ * DR_) / 32, C_ / 32), blk, 0, stream>>>(W_qr, Wt_qr, C_, H_ * DR_);
  transpose_w_kernel<<<dim3(E_ / 32, E_ / 32), blk, 0, stream>>>(W_out, Wt_out, E_, E_);

  // fused projection 1: [c_kv | c_q | k_rot_pre] = h @ [W_dkv|W_dq|W_kr]
  // N=1536 -> 384 blocks (was 3x128 half-idle launches)
  mfma_gemm<<<dim3(1536 / 128, M_ / 128), blk, 0, stream>>>(
      h_bf, Wt_dkv,
      mkseg(out_ckv, ckv_bf, b_dkv, nullptr, C_, C_, C_, 0, 0),
      mkseg(nullptr, cq_bf,  b_dq,  nullptr, C_, C_, C_, 0, 512),
      mkseg(nullptr, k_bf,   b_kr,  nullptr, 2048, DR_, DH_, SP_, 1024),
      E_);
  // k = c_kv @ W_uk (head-remapped into k_bf cols [0,96) per head)
  mfma_gemm<<<dim3((H_ * SP_) / 128, M_ / 128), blk, 0, stream>>>(
      ckv_bf, Wt_uk,
      mkseg(nullptr, k_bf, b_uk, nullptr, 2048, SP_, DH_, 0, 0),
      segnone(), segnone(), C_);
  // V^T = W_uv^T @ c_kv^T : swapped operands -> output rows = h*128+d,
  // cols = b*2048+s. biasM = b_uv (row axis).
  mfma_gemm<<<dim3(M_ / 128, (H_ * DH_) / 128), blk, 0, stream>>>(
      Wt_uv, ckv_bf,
      mkseg(nullptr, vt_bf, nullptr, b_uv, M_, M_, M_, 0, 0),
      segnone(), segnone(), C_);
  // fused projection 2: [q_base | q_rot_pre] = c_q @ [W_uq|W_qr], N=2048
  mfma_gemm<<<dim3(2048 / 128, M_ / 128), blk, 0, stream>>>(
      cq_bf, Wt_uq,
      mkseg(nullptr, q_bf, b_uq, nullptr, 2048, SP_, DH_, 0, 0),
      mkseg(nullptr, q_bf, b_qr, nullptr, 2048, DR_, DH_, SP_, 1536),
      segnone(), C_);

  rope_kernel<<<(M_ * H_ * 8) / 256, blk, 0, stream>>>(q_bf, k_bf, out_krot);
  // paired-q flash attention: grid = B*H*16 = 512, XCD-swizzled in-kernel
  attn_kernel<<<B_ * H_ * 16, blk, 0, stream>>>(q_bf, k_bf, vt_bf, ao_bf);

  // out = ao @ W_out + b  (fp32 -> d_out region 0)
  mfma_gemm<<<dim3(E_ / 128, M_ / 128), blk, 0, stream>>>(
      ao_bf, Wt_out,
      mkseg(out, nullptr, b_out, nullptr, E_, E_, E_, 0, 0),
      segnone(), segnone(), E_);
}

// Round 2
// 427.499 us; speedup vs baseline: 1.3675x; 1.0201x over previous
//
#include <hip/hip_runtime.h>
#include <hip/hip_bf16.h>

// MLA forward. Storage fp32 in/out; internal pipeline bf16 MFMA, fp32 accum.
// R2 changes vs R1 (436us):
//  - mfma_gemm: 2-phase double-buffered pipeline (prefetch tile t+1 via
//    global_load_lds before computing tile t; one barrier-drain per tile).
//  - attn: grid 1024 (one q-tile/block, longest-first) -> 4 blocks/CU;
//    T14 async staging (global->reg issued before compute, LDS write after);
//    P stored k-interleaved via v_cvt_pk_bf16_f32 (1 op vs 2x manual f2bf),
//    V^T columns pre-interleaved in its GEMM epilogue to match;
//    Q pre-scaled (qscale*log2e folded into q-projection epilogue).
#define B_   2
#define S_   2048
#define E_   2048
#define H_   16
#define DH_  128
#define DR_  32
#define SP_  96
#define C_   512
#define M_   (B_ * S_)   // 4096 rows

#define LOG2E 1.4426950408889634f

typedef __attribute__((ext_vector_type(8))) short short8;
typedef __attribute__((ext_vector_type(4))) float floatx4;

__device__ __forceinline__ float bfu(unsigned short u) {
  return __uint_as_float((unsigned)u << 16);
}
__device__ __forceinline__ unsigned short f2bf(float f) {
  unsigned u = __float_as_uint(f);
  return (unsigned short)((u + 0x7fff + ((u >> 16) & 1)) >> 16);  // RNE
}

// async global->LDS, 16B per lane. LDS dest: wave-uniform base + lane*16.
__device__ __forceinline__ void gload16(const void* g, void* l) {
  __builtin_amdgcn_global_load_lds(
      (const __attribute__((address_space(1))) void*)g,
      (__attribute__((address_space(3))) void*)l, 16, 0, 0);
}

// ---------- fp32 -> bf16 bulk convert (for h) ----------
__global__ __launch_bounds__(256) void f2bf_kernel(
    const float* __restrict__ src, unsigned short* __restrict__ dst) {
  size_t i = ((size_t)blockIdx.x * 256 + threadIdx.x) * 4;
  float4 v = *(const float4*)(src + i);
  ushort4 w;
  w.x = f2bf(v.x); w.y = f2bf(v.y); w.z = f2bf(v.z); w.w = f2bf(v.w);
  *(ushort4*)(dst + i) = w;
}

// ---------- W[K][N] fp32 -> Wt[N][K] bf16 ----------
__global__ __launch_bounds__(256) void transpose_w_kernel(
    const float* __restrict__ W, unsigned short* __restrict__ Wt, int K, int N) {
  __shared__ unsigned short T[32][33];
  int n0 = blockIdx.x * 32, k0 = blockIdx.y * 32;
  int t = threadIdx.x, lane = t & 31, grp = t >> 5;
#pragma unroll
  for (int p = 0; p < 4; p++) {
    int k = p * 8 + grp;
    T[lane][k] = f2bf(W[(size_t)(k0 + k) * N + n0 + lane]);
  }
  __syncthreads();
#pragma unroll
  for (int p = 0; p < 4; p++) {
    int n = p * 8 + grp;
    Wt[(size_t)(n0 + n) * K + k0 + lane] = T[n][lane];
  }
}

// ---------- bf16 MFMA GEMM, multi-segment epilogue, 2-phase pipeline ----------
// C = A(MxK) @ Wt(NxK)^T. Segment per 128-col block range; within a segment:
//   n_local = n - nstart; col = obase + (nl/chunk)*gstride + nl%chunk;
//   if ileave: col permuted within its 32-block (attn V k-interleave);
//   val = (acc + bias) * oscale. biasM = row-indexed bias (V^T projection).
struct Seg {
  float* outF;
  unsigned short* outB;
  const float* bias;    // indexed by n_local
  const float* biasM;   // indexed by m (overrides bias)
  int orow, chunk, gstride, obase, nstart, ileave;
  float oscale;
};

__global__ __launch_bounds__(256) void mfma_gemm(
    const unsigned short* __restrict__ A, const unsigned short* __restrict__ Wt,
    Seg s0, Seg s1, Seg s2, int K) {
  __shared__ unsigned short As0[128 * 32];
  __shared__ unsigned short Bs0[128 * 32];
  __shared__ unsigned short As1[128 * 32];
  __shared__ unsigned short Bs1[128 * 32];
  int tid = threadIdx.x;
  int lane = tid & 63, wave = tid >> 6;
  int l16 = lane & 15, quad = lane >> 4;
  int bm = blockIdx.y * 128, bn = blockIdx.x * 128;
  int wm = (wave & 1) * 64, wn = (wave >> 1) * 64;

  floatx4 acc[4][4];
#pragma unroll
  for (int mt = 0; mt < 4; mt++)
#pragma unroll
    for (int nt = 0; nt < 4; nt++) acc[mt][nt] = (floatx4){0.f, 0.f, 0.f, 0.f};

  // staging: 8 chunks of 1KB per operand; wave w owns chunks 2w,2w+1.
  int c0 = wave * 2, c1 = c0 + 1;
  int srow = lane >> 2, scol = (lane & 3) * 8;
  const unsigned short* Ag0 = A + (size_t)(bm + c0 * 16 + srow) * K + scol;
  const unsigned short* Ag1 = A + (size_t)(bm + c1 * 16 + srow) * K + scol;
  const unsigned short* Bg0 = Wt + (size_t)(bn + c0 * 16 + srow) * K + scol;
  const unsigned short* Bg1 = Wt + (size_t)(bn + c1 * 16 + srow) * K + scol;

#define GSTAGE(kk, Asb, Bsb) do {            \
    gload16(Ag0 + (kk), &Asb[c0 * 512]);     \
    gload16(Ag1 + (kk), &Asb[c1 * 512]);     \
    gload16(Bg0 + (kk), &Bsb[c0 * 512]);     \
    gload16(Bg1 + (kk), &Bsb[c1 * 512]); } while (0)

#define GCOMPUTE(Asb, Bsb) do {                                            \
    short8 af[4], bfv[4];                                                  \
    _Pragma("unroll")                                                      \
    for (int mt = 0; mt < 4; mt++)                                         \
      af[mt] = *(const short8*)&Asb[(wm + mt * 16 + l16) * 32 + quad * 8]; \
    _Pragma("unroll")                                                      \
    for (int nt = 0; nt < 4; nt++)                                         \
      bfv[nt] = *(const short8*)&Bsb[(wn + nt * 16 + l16) * 32 + quad * 8];\
    _Pragma("unroll")                                                      \
    for (int mt = 0; mt < 4; mt++)                                         \
      _Pragma("unroll")                                                    \
      for (int nt = 0; nt < 4; nt++)                                       \
        acc[mt][nt] = __builtin_amdgcn_mfma_f32_16x16x32_bf16(             \
            af[mt], bfv[nt], acc[mt][nt], 0, 0, 0); } while (0)

  // 2-phase pipeline: prefetch next 32-K tile while computing current.
  // K % 64 == 0 for all call sites.
  GSTAGE(0, As0, Bs0);
  __syncthreads();
  for (int k0 = 0; k0 < K; k0 += 64) {
    GSTAGE(k0 + 32, As1, Bs1);
    GCOMPUTE(As0, Bs0);
    __syncthreads();
    if (k0 + 64 < K) GSTAGE(k0 + 64, As0, Bs0);
    GCOMPUTE(As1, Bs1);
    __syncthreads();
  }
#undef GSTAGE
#undef GCOMPUTE

  Seg sg = (bn >= s2.nstart) ? s2 : ((bn >= s1.nstart) ? s1 : s0);

  // C/D layout: D[row=quad*4+r][col=l16]
#pragma unroll
  for (int mt = 0; mt < 4; mt++) {
    int m0 = bm + wm + mt * 16 + quad * 4;
    float bm4[4] = {0.f, 0.f, 0.f, 0.f};
    if (sg.biasM) {
#pragma unroll
      for (int r = 0; r < 4; r++) bm4[r] = sg.biasM[m0 + r];
    }
#pragma unroll
    for (int nt = 0; nt < 4; nt++) {
      int n = bn + wn + nt * 16 + l16;
      int nl = n - sg.nstart;
      float bv = sg.biasM ? 0.f : sg.bias[nl];
      int ncol = sg.obase + (nl / sg.chunk) * sg.gstride + (nl % sg.chunk);
      if (sg.ileave)
        ncol = (ncol & ~31) | ((ncol & 15) << 1) | ((ncol >> 4) & 1);
#pragma unroll
      for (int r = 0; r < 4; r++) {
        float val = (acc[mt][nt][r] + (sg.biasM ? bm4[r] : bv)) * sg.oscale;
        size_t idx = (size_t)(m0 + r) * sg.orow + ncol;
        if (sg.outF) sg.outF[idx] = val;
        if (sg.outB) sg.outB[idx] = f2bf(val);
      }
    }
  }
}

// ---------- RoPE on bf16 q/k; fp32 k_rot to d_out ----------
// q values arrive pre-scaled by qscale; rotation commutes with scalar scale.
__global__ __launch_bounds__(256) void rope_kernel(
    unsigned short* __restrict__ qf, unsigned short* __restrict__ kf,
    float* __restrict__ krot_out) {
  int idx = blockIdx.x * 256 + threadIdx.x;
  int j  = idx & 7;
  int h  = (idx >> 3) & (H_ - 1);
  int bs = idx >> 7;
  if (bs >= M_) return;
  int s = bs & (S_ - 1);
  float t = (float)s / 40.0f;
  float ang = t * exp2f(-1.6609640474436813f * (float)j);  // 10000^(-j/8)
  float c = cosf(ang), sn = sinf(ang);

  size_t base = (size_t)bs * 2048 + h * 128 + 96;
  float x0 = bfu(qf[base + j]), x1 = bfu(qf[base + j + 8]);
  qf[base + j]     = f2bf(x0 * c - x1 * sn);
  qf[base + j + 8] = f2bf(x1 * c + x0 * sn);

  float y0 = bfu(kf[base + j]), y1 = bfu(kf[base + j + 8]);
  float r0 = y0 * c - y1 * sn;
  float r1 = y1 * c + y0 * sn;
  kf[base + j]     = f2bf(r0);
  kf[base + j + 8] = f2bf(r1);

  size_t ko = (size_t)bs * (H_ * DR_) + h * DR_;
  krot_out[ko + j]      = r0;
  krot_out[ko + j + 8]  = r1;
  krot_out[ko + 16 + j] = bfu(kf[base + 16 + j]);
  krot_out[ko + 24 + j] = bfu(kf[base + 24 + j]);
}

// ---------- flash attention: one q-tile per block, T14 async staging ----------
// vt layout: [h*128+d][b*2048+s], s interleaved per 32-block (phys 2k,2k+1 =
// logical k, k+16) to match the cvt_pk-packed P. Grid 1024; XCD x owns 4 bh.
#define KST 136
#define VST 40
#define PST 40
__global__ __launch_bounds__(256) void attn_kernel(
    const unsigned short* __restrict__ qf, const unsigned short* __restrict__ kf,
    const unsigned short* __restrict__ vt, unsigned short* __restrict__ ao) {
  __shared__ unsigned short Ks[32 * KST];
  __shared__ unsigned short Vs[128 * VST];
  __shared__ unsigned short Ps[4][16 * PST];

  int bid0 = blockIdx.x;            // 0..1023
  int xcd  = bid0 & 7;              // HW XCD (round-robin dispatch)
  int idx  = bid0 >> 3;             // 0..127 within XCD
  int bh   = xcd * 4 + (idx >> 5);  // 4 bh per XCD -> K/V fits its L2
  int jj   = 31 - (idx & 31);       // q-tile, longest-first
  int h    = bh & 15;
  int b    = bh >> 4;
  int q0   = jj << 6;

  int tid  = threadIdx.x;
  int wave = tid >> 6;
  int lane = tid & 63;
  int l16  = lane & 15;
  int quad = lane >> 4;

  // staging maps
  int srow  = tid >> 3;          // K rows 0..31
  int sd0   = (tid & 7) * 16;    // K d-offset
  int vrow  = tid >> 1;          // Vt rows 0..127 (d)
  int vhalf = (tid & 1) * 16;    // Vt k-offset

  // Q fragments: pre-scaled by qscale*log2e in the projection epilogue.
  int qrow = q0 + wave * 16 + l16;
  const unsigned short* qbase =
      qf + ((size_t)(b * S_ + qrow)) * 2048 + h * 128 + quad * 8;
  short8 qfrag[4];
#pragma unroll
  for (int c = 0; c < 4; c++) qfrag[c] = *(const short8*)(qbase + c * 32);

  floatx4 Oacc[8];
#pragma unroll
  for (int dt = 0; dt < 8; dt++) Oacc[dt] = (floatx4){0.f, 0.f, 0.f, 0.f};
  float lpart[4] = {0.f, 0.f, 0.f, 0.f};

  int qg_lo = q0 + wave * 16;
  int qg_hi = qg_lo + 15;
  int nkt = (q0 >> 5) + 2;

  const unsigned short* kbase =
      kf + ((size_t)(b * S_ + srow)) * 2048 + h * 128 + sd0;
  const unsigned short* vbase =
      vt + ((size_t)(h * 128 + vrow)) * 4096 + b * 2048 + vhalf;
  unsigned short* kd = &Ks[srow * KST + sd0];
  unsigned short* vd = &Vs[vrow * VST + vhalf];

  short8 kr0, kr1, vr0, vr1;
  // prologue: stage kt=0
  kr0 = *(const short8*)kbase;
  kr1 = *(const short8*)(kbase + 8);
  vr0 = *(const short8*)vbase;
  vr1 = *(const short8*)(vbase + 8);
  *(short8*)kd = kr0; *(short8*)(kd + 8) = kr1;
  *(short8*)vd = vr0; *(short8*)(vd + 8) = vr1;
  __syncthreads();

  for (int kt = 0; kt < nkt; kt++) {
    bool more = (kt + 1 < nkt);
    if (more) {  // T14: issue next-tile global loads before compute
      const unsigned short* ks = kbase + (size_t)(kt + 1) * 32 * 2048;
      kr0 = *(const short8*)ks;
      kr1 = *(const short8*)(ks + 8);
      const unsigned short* vs = vbase + (kt + 1) * 32;
      vr0 = *(const short8*)vs;
      vr1 = *(const short8*)(vs + 8);
    }
    int kt0 = kt << 5;
    if (kt0 <= qg_hi) {
      floatx4 s0v = {0.f, 0.f, 0.f, 0.f}, s1v = {0.f, 0.f, 0.f, 0.f};
#pragma unroll
      for (int c = 0; c < 4; c++) {
        short8 kfr = *(const short8*)&Ks[l16 * KST + c * 32 + quad * 8];
        s0v = __builtin_amdgcn_mfma_f32_16x16x32_bf16(qfrag[c], kfr, s0v, 0, 0, 0);
      }
#pragma unroll
      for (int c = 0; c < 4; c++) {
        short8 kfr = *(const short8*)&Ks[(16 + l16) * KST + c * 32 + quad * 8];
        s1v = __builtin_amdgcn_mfma_f32_16x16x32_bf16(qfrag[c], kfr, s1v, 0, 0, 0);
      }

      unsigned short* P = Ps[wave];
      bool diag = (kt0 + 31 > qg_lo);
#pragma unroll
      for (int r = 0; r < 4; r++) {
        float p0 = exp2f(fminf(s0v[r], 80.f));
        float p1 = exp2f(fminf(s1v[r], 80.f));
        if (diag) {
          int q_r = qg_lo + quad * 4 + r;
          if (kt0 + l16 > q_r)      p0 = 0.f;
          if (kt0 + 16 + l16 > q_r) p1 = 0.f;
        }
        unsigned pk;  // lo=bf16(p0) at phys 2*l16 (k=l16), hi=bf16(p1) (k=16+l16)
        asm("v_cvt_pk_bf16_f32 %0, %1, %2" : "=v"(pk) : "v"(p0), "v"(p1));
        *(unsigned*)&P[(quad * 4 + r) * PST + 2 * l16] = pk;
        lpart[r] += p0 + p1;
      }

      short8 pfrag = *(const short8*)&P[l16 * PST + quad * 8];
#pragma unroll
      for (int dt = 0; dt < 8; dt++) {
        short8 vfr = *(const short8*)&Vs[(dt * 16 + l16) * VST + quad * 8];
        Oacc[dt] = __builtin_amdgcn_mfma_f32_16x16x32_bf16(pfrag, vfr, Oacc[dt], 0, 0, 0);
      }
    }
    if (more) {
      __syncthreads();  // all waves done reading current tile
      *(short8*)kd = kr0; *(short8*)(kd + 8) = kr1;
      *(short8*)vd = vr0; *(short8*)(vd + 8) = vr1;
      __syncthreads();  // next tile visible
    }
  }

  // epilogue: one l-reduction per q-tile
  float linv[4];
#pragma unroll
  for (int r = 0; r < 4; r++) {
    float ls = lpart[r];
#pragma unroll
    for (int sh = 1; sh < 16; sh <<= 1) ls += __shfl_xor(ls, sh);
    linv[r] = 1.0f / ls;
  }
  int qg = q0 + wave * 16 + quad * 4;
#pragma unroll
  for (int r = 0; r < 4; r++) {
    unsigned short* dst = ao + ((size_t)(b * S_ + qg + r)) * 2048 + h * 128 + l16;
#pragma unroll
    for (int dt = 0; dt < 8; dt++) dst[dt * 16] = f2bf(Oacc[dt][r] * linv[r]);
  }
}

static inline Seg mkseg(float* oF, unsigned short* oB, const float* bias,
                        const float* biasM, int orow, int chunk, int gstride,
                        int obase, int nstart, int ileave, float oscale) {
  Seg s;
  s.outF = oF; s.outB = oB; s.bias = bias; s.biasM = biasM;
  s.orow = orow; s.chunk = chunk; s.gstride = gstride;
  s.obase = obase; s.nstart = nstart; s.ileave = ileave; s.oscale = oscale;
  return s;
}
static inline Seg segnone() {
  return mkseg(nullptr, nullptr, nullptr, nullptr, 1, 1, 1, 0, 0x7fffffff, 0, 1.f);
}

extern "C" void kernel_launch(void* const* d_in, const int* in_sizes, int n_in,
                              void* d_out, int out_size, void* d_ws, size_t ws_size,
                              hipStream_t stream) {
  const float* h     = (const float*)d_in[0];
  const float* W_dkv = (const float*)d_in[1];
  const float* b_dkv = (const float*)d_in[2];
  const float* W_dq  = (const float*)d_in[3];
  const float* b_dq  = (const float*)d_in[4];
  const float* W_uk  = (const float*)d_in[5];
  const float* b_uk  = (const float*)d_in[6];
  const float* W_uv  = (const float*)d_in[7];
  const float* b_uv  = (const float*)d_in[8];
  const float* W_uq  = (const float*)d_in[9];
  const float* b_uq  = (const float*)d_in[10];
  const float* W_qr  = (const float*)d_in[11];
  const float* b_qr  = (const float*)d_in[12];
  const float* W_kr  = (const float*)d_in[13];
  const float* b_kr  = (const float*)d_in[14];
  const float* W_out = (const float*)d_in[15];
  const float* b_out = (const float*)d_in[16];

  float* out      = (float*)d_out;
  float* out_ckv  = out + (size_t)M_ * E_;
  float* out_krot = out_ckv + (size_t)M_ * C_;

  unsigned short* w16 = (unsigned short*)d_ws;
  unsigned short* h_bf   = w16;                 //  8,388,608
  unsigned short* q_bf   = w16 + 8388608;       //  8,388,608
  unsigned short* k_bf   = w16 + 16777216;      //  8,388,608
  unsigned short* vt_bf  = w16 + 25165824;      //  8,388,608  (V^T, s interleaved)
  unsigned short* ao_bf  = w16 + 33554432;      //  8,388,608
  unsigned short* ckv_bf = w16 + 41943040;      //  2,097,152
  unsigned short* cq_bf  = w16 + 44040192;      //  2,097,152
  // fused weight 1: rows [0,512)=W_dkv^T, [512,1024)=W_dq^T, [1024,1536)=W_kr^T
  unsigned short* Wt_dkv = w16 + 46137344;      //  1,048,576
  unsigned short* Wt_dq  = w16 + 47185920;      //  1,048,576 (= WtF1 + 512*2048)
  unsigned short* Wt_kr  = w16 + 48234496;      //  1,048,576 (= WtF1 + 1024*2048)
  unsigned short* Wt_uk  = w16 + 49283072;      //    786,432
  unsigned short* Wt_uv  = w16 + 50069504;      //  1,048,576
  // fused weight 2: rows [0,1536)=W_uq^T, [1536,2048)=W_qr^T
  unsigned short* Wt_uq  = w16 + 51118080;      //    786,432
  unsigned short* Wt_qr  = w16 + 51904512;      //    262,144 (= WtF2 + 1536*512)
  unsigned short* Wt_out = w16 + 52166656;      //  4,194,304

  dim3 blk(256);
  const float qscale = 0.08838834764831845f * LOG2E;  // 1/sqrt(128)*log2(e)

  // conversions / transposes
  f2bf_kernel<<<8192, blk, 0, stream>>>(h, h_bf);
  transpose_w_kernel<<<dim3(C_ / 32, E_ / 32), blk, 0, stream>>>(W_dkv, Wt_dkv, E_, C_);
  transpose_w_kernel<<<dim3(C_ / 32, E_ / 32), blk, 0, stream>>>(W_dq, Wt_dq, E_, C_);
  transpose_w_kernel<<<dim3((H_ * DR_) / 32, E_ / 32), blk, 0, stream>>>(W_kr, Wt_kr, E_, H_ * DR_);
  transpose_w_kernel<<<dim3((H_ * SP_) / 32, C_ / 32), blk, 0, stream>>>(W_uk, Wt_uk, C_, H_ * SP_);
  transpose_w_kernel<<<dim3((H_ * DH_) / 32, C_ / 32), blk, 0, stream>>>(W_uv, Wt_uv, C_, H_ * DH_);
  transpose_w_kernel<<<dim3((H_ * SP_) / 32, C_ / 32), blk, 0, stream>>>(W_uq, Wt_uq, C_, H_ * SP_);
  transpose_w_kernel<<<dim3((H_ * DR_) / 32, C_ / 32), blk, 0, stream>>>(W_qr, Wt_qr, C_, H_ * DR_);
  transpose_w_kernel<<<dim3(E_ / 32, E_ / 32), blk, 0, stream>>>(W_out, Wt_out, E_, E_);

  // fused projection 1: [c_kv | c_q | k_rot_pre] = h @ [W_dkv|W_dq|W_kr]
  mfma_gemm<<<dim3(1536 / 128, M_ / 128), blk, 0, stream>>>(
      h_bf, Wt_dkv,
      mkseg(out_ckv, ckv_bf, b_dkv, nullptr, C_, C_, C_, 0, 0, 0, 1.f),
      mkseg(nullptr, cq_bf,  b_dq,  nullptr, C_, C_, C_, 0, 512, 0, 1.f),
      mkseg(nullptr, k_bf,   b_kr,  nullptr, 2048, DR_, DH_, SP_, 1024, 0, 1.f),
      E_);
  // k = c_kv @ W_uk (head-remapped into k_bf cols [0,96) per head)
  mfma_gemm<<<dim3((H_ * SP_) / 128, M_ / 128), blk, 0, stream>>>(
      ckv_bf, Wt_uk,
      mkseg(nullptr, k_bf, b_uk, nullptr, 2048, SP_, DH_, 0, 0, 0, 1.f),
      segnone(), segnone(), C_);
  // V^T = W_uv^T @ c_kv^T (swapped operands); s-columns interleaved per
  // 32-block to match cvt_pk-packed P in attention. biasM = b_uv (row axis).
  mfma_gemm<<<dim3(M_ / 128, (H_ * DH_) / 128), blk, 0, stream>>>(
      Wt_uv, ckv_bf,
      mkseg(nullptr, vt_bf, nullptr, b_uv, M_, M_, M_, 0, 0, 1, 1.f),
      segnone(), segnone(), C_);
  // fused projection 2: [q_base | q_rot_pre] = c_q @ [W_uq|W_qr], pre-scaled
  mfma_gemm<<<dim3(2048 / 128, M_ / 128), blk, 0, stream>>>(
      cq_bf, Wt_uq,
      mkseg(nullptr, q_bf, b_uq, nullptr, 2048, SP_, DH_, 0, 0, 0, qscale),
      mkseg(nullptr, q_bf, b_qr, nullptr, 2048, DR_, DH_, SP_, 1536, 0, qscale),
      segnone(), C_);

  rope_kernel<<<(M_ * H_ * 8) / 256, blk, 0, stream>>>(q_bf, k_bf, out_krot);
  // one q-tile per block: grid = B*H*32 = 1024, XCD-swizzled in-kernel
  attn_kernel<<<B_ * H_ * 32, blk, 0, stream>>>(q_bf, k_bf, vt_bf, ao_bf);

  // out = ao @ W_out + b  (fp32 -> d_out region 0)
  mfma_gemm<<<dim3(E_ / 128, M_ / 128), blk, 0, stream>>>(
      ao_bf, Wt_out,
      mkseg(out, nullptr, b_out, nullptr, E_, E_, E_, 0, 0, 0, 1.f),
      segnone(), segnone(), E_);
}

// Round 4
// 375.762 us; speedup vs baseline: 1.5558x; 1.1377x over previous
//
#include <hip/hip_runtime.h>
#include <hip/hip_bf16.h>

// MLA forward. Storage fp32 in/out; internal pipeline bf16 MFMA, fp32 accum.
// R4 = R3 resubmit (container infra failure), compound literals hardened.
// R3 changes vs R2 (427us):
//  - attn: paired q-tiles restored (uniform work per CU; R2's 1024-grid put
//    equal-length tiles on the same CU -> CU0 did 32x CU31's work);
//    K/V LDS double-buffered, ONE barrier per k-tile (write next-buf from
//    regs, prefetch t+2, compute, sync); setprio around MFMA clusters.
//    Keeps R2's cvt_pk P-pack, interleaved V^T, pre-scaled Q.
//  - mfma_gemm: bijective XCD block swizzle (contiguous tile chunk per XCD;
//    all grids %8==0) on top of the 2-phase gload_lds pipeline.
//  - 8 transpose launches merged into one (segment table, unrolled select).
#define B_   2
#define S_   2048
#define E_   2048
#define H_   16
#define DH_  128
#define DR_  32
#define SP_  96
#define C_   512
#define M_   (B_ * S_)   // 4096 rows

#define LOG2E 1.4426950408889634f

typedef __attribute__((ext_vector_type(8))) short short8;
typedef __attribute__((ext_vector_type(4))) float floatx4;

__device__ __forceinline__ float bfu(unsigned short u) {
  return __uint_as_float((unsigned)u << 16);
}
__device__ __forceinline__ unsigned short f2bf(float f) {
  unsigned u = __float_as_uint(f);
  return (unsigned short)((u + 0x7fff + ((u >> 16) & 1)) >> 16);  // RNE
}

// async global->LDS, 16B per lane. LDS dest: wave-uniform base + lane*16.
__device__ __forceinline__ void gload16(const void* g, void* l) {
  __builtin_amdgcn_global_load_lds(
      (const __attribute__((address_space(1))) void*)g,
      (__attribute__((address_space(3))) void*)l, 16, 0, 0);
}

// ---------- fp32 -> bf16 bulk convert (for h) ----------
__global__ __launch_bounds__(256) void f2bf_kernel(
    const float* __restrict__ src, unsigned short* __restrict__ dst) {
  size_t i = ((size_t)blockIdx.x * 256 + threadIdx.x) * 4;
  float4 v = *(const float4*)(src + i);
  ushort4 w;
  w.x = f2bf(v.x); w.y = f2bf(v.y); w.z = f2bf(v.z); w.w = f2bf(v.w);
  *(ushort4*)(dst + i) = w;
}

// ---------- all 8 weight transposes in ONE launch ----------
// W[K][N] fp32 -> Wt[N][K] bf16, 32x32 tiles; entry picked by block range.
struct TEnt { const float* W; unsigned short* Wt; int K, N, ntiles, nx; };
struct TTab { TEnt e[8]; };

__global__ __launch_bounds__(256) void transpose_all_kernel(TTab tab) {
  __shared__ unsigned short T[32][33];
  int rem = blockIdx.x;
  const float* W = nullptr; unsigned short* Wt = nullptr;
  int K = 0, N = 0, nx = 1;
  bool done = false;
#pragma unroll
  for (int j = 0; j < 8; j++) {   // constant-index select (stays in SGPRs)
    if (!done) {
      if (rem < tab.e[j].ntiles) {
        W = tab.e[j].W; Wt = tab.e[j].Wt;
        K = tab.e[j].K; N = tab.e[j].N; nx = tab.e[j].nx;
        done = true;
      } else {
        rem -= tab.e[j].ntiles;
      }
    }
  }
  int n0 = (rem % nx) * 32, k0 = (rem / nx) * 32;
  int t = threadIdx.x, lane = t & 31, grp = t >> 5;
#pragma unroll
  for (int p = 0; p < 4; p++) {
    int k = p * 8 + grp;
    T[lane][k] = f2bf(W[(size_t)(k0 + k) * N + n0 + lane]);
  }
  __syncthreads();
#pragma unroll
  for (int p = 0; p < 4; p++) {
    int n = p * 8 + grp;
    Wt[(size_t)(n0 + n) * K + k0 + lane] = T[n][lane];
  }
}

// ---------- bf16 MFMA GEMM, multi-segment epilogue, 2-phase pipeline ----------
// C = A(MxK) @ Wt(NxK)^T. Segment per 128-col block range; within a segment:
//   n_local = n - nstart; col = obase + (nl/chunk)*gstride + nl%chunk;
//   if ileave: col permuted within its 32-block (attn V k-interleave);
//   val = (acc + bias) * oscale. biasM = row-indexed bias (V^T projection).
// Blocks XCD-swizzled: XCD x owns tiles [x*nwg/8, (x+1)*nwg/8) in row-major
// tile order -> A row-panels become XCD-L2 resident. Requires nwg % 8 == 0.
struct Seg {
  float* outF;
  unsigned short* outB;
  const float* bias;    // indexed by n_local
  const float* biasM;   // indexed by m (overrides bias)
  int orow, chunk, gstride, obase, nstart, ileave;
  float oscale;
};

__global__ __launch_bounds__(256) void mfma_gemm(
    const unsigned short* __restrict__ A, const unsigned short* __restrict__ Wt,
    Seg s0, Seg s1, Seg s2, int K) {
  __shared__ unsigned short As0[128 * 32];
  __shared__ unsigned short Bs0[128 * 32];
  __shared__ unsigned short As1[128 * 32];
  __shared__ unsigned short Bs1[128 * 32];
  int tid = threadIdx.x;
  int lane = tid & 63, wave = tid >> 6;
  int l16 = lane & 15, quad = lane >> 4;

  // XCD swizzle (bijective; nwg % 8 == 0 at every call site)
  int gx = gridDim.x;
  int nwg = gx * gridDim.y;
  int flat = blockIdx.y * gx + blockIdx.x;
  int w = (flat & 7) * (nwg >> 3) + (flat >> 3);
  int by = w / gx, bx = w - by * gx;
  int bm = by * 128, bn = bx * 128;
  int wm = (wave & 1) * 64, wn = (wave >> 1) * 64;

  floatx4 acc[4][4];
#pragma unroll
  for (int mt = 0; mt < 4; mt++)
#pragma unroll
    for (int nt = 0; nt < 4; nt++) acc[mt][nt] = (floatx4){0.f, 0.f, 0.f, 0.f};

  // staging: 8 chunks of 1KB per operand; wave w owns chunks 2w,2w+1.
  int c0 = wave * 2, c1 = c0 + 1;
  int srow = lane >> 2, scol = (lane & 3) * 8;
  const unsigned short* Ag0 = A + (size_t)(bm + c0 * 16 + srow) * K + scol;
  const unsigned short* Ag1 = A + (size_t)(bm + c1 * 16 + srow) * K + scol;
  const unsigned short* Bg0 = Wt + (size_t)(bn + c0 * 16 + srow) * K + scol;
  const unsigned short* Bg1 = Wt + (size_t)(bn + c1 * 16 + srow) * K + scol;

#define GSTAGE(kk, Asb, Bsb) do {            \
    gload16(Ag0 + (kk), &Asb[c0 * 512]);     \
    gload16(Ag1 + (kk), &Asb[c1 * 512]);     \
    gload16(Bg0 + (kk), &Bsb[c0 * 512]);     \
    gload16(Bg1 + (kk), &Bsb[c1 * 512]); } while (0)

#define GCOMPUTE(Asb, Bsb) do {                                            \
    short8 af[4], bfv[4];                                                  \
    _Pragma("unroll")                                                      \
    for (int mt = 0; mt < 4; mt++)                                         \
      af[mt] = *(const short8*)&Asb[(wm + mt * 16 + l16) * 32 + quad * 8]; \
    _Pragma("unroll")                                                      \
    for (int nt = 0; nt < 4; nt++)                                         \
      bfv[nt] = *(const short8*)&Bsb[(wn + nt * 16 + l16) * 32 + quad * 8];\
    _Pragma("unroll")                                                      \
    for (int mt = 0; mt < 4; mt++)                                         \
      _Pragma("unroll")                                                    \
      for (int nt = 0; nt < 4; nt++)                                       \
        acc[mt][nt] = __builtin_amdgcn_mfma_f32_16x16x32_bf16(             \
            af[mt], bfv[nt], acc[mt][nt], 0, 0, 0); } while (0)

  // 2-phase pipeline: prefetch next 32-K tile while computing current.
  // K % 64 == 0 for all call sites.
  GSTAGE(0, As0, Bs0);
  __syncthreads();
  for (int k0 = 0; k0 < K; k0 += 64) {
    GSTAGE(k0 + 32, As1, Bs1);
    GCOMPUTE(As0, Bs0);
    __syncthreads();
    if (k0 + 64 < K) GSTAGE(k0 + 64, As0, Bs0);
    GCOMPUTE(As1, Bs1);
    __syncthreads();
  }
#undef GSTAGE
#undef GCOMPUTE

  Seg sg = (bn >= s2.nstart) ? s2 : ((bn >= s1.nstart) ? s1 : s0);

  // C/D layout: D[row=quad*4+r][col=l16]
#pragma unroll
  for (int mt = 0; mt < 4; mt++) {
    int m0 = bm + wm + mt * 16 + quad * 4;
    float bm4[4] = {0.f, 0.f, 0.f, 0.f};
    if (sg.biasM) {
#pragma unroll
      for (int r = 0; r < 4; r++) bm4[r] = sg.biasM[m0 + r];
    }
#pragma unroll
    for (int nt = 0; nt < 4; nt++) {
      int n = bn + wn + nt * 16 + l16;
      int nl = n - sg.nstart;
      float bv = sg.biasM ? 0.f : sg.bias[nl];
      int ncol = sg.obase + (nl / sg.chunk) * sg.gstride + (nl % sg.chunk);
      if (sg.ileave)
        ncol = (ncol & ~31) | ((ncol & 15) << 1) | ((ncol >> 4) & 1);
#pragma unroll
      for (int r = 0; r < 4; r++) {
        float val = (acc[mt][nt][r] + (sg.biasM ? bm4[r] : bv)) * sg.oscale;
        size_t idx = (size_t)(m0 + r) * sg.orow + ncol;
        if (sg.outF) sg.outF[idx] = val;
        if (sg.outB) sg.outB[idx] = f2bf(val);
      }
    }
  }
}

// ---------- RoPE on bf16 q/k; fp32 k_rot to d_out ----------
// q values arrive pre-scaled by qscale; rotation commutes with scalar scale.
__global__ __launch_bounds__(256) void rope_kernel(
    unsigned short* __restrict__ qf, unsigned short* __restrict__ kf,
    float* __restrict__ krot_out) {
  int idx = blockIdx.x * 256 + threadIdx.x;
  int j  = idx & 7;
  int h  = (idx >> 3) & (H_ - 1);
  int bs = idx >> 7;
  if (bs >= M_) return;
  int s = bs & (S_ - 1);
  float t = (float)s / 40.0f;
  float ang = t * exp2f(-1.6609640474436813f * (float)j);  // 10000^(-j/8)
  float c = cosf(ang), sn = sinf(ang);

  size_t base = (size_t)bs * 2048 + h * 128 + 96;
  float x0 = bfu(qf[base + j]), x1 = bfu(qf[base + j + 8]);
  qf[base + j]     = f2bf(x0 * c - x1 * sn);
  qf[base + j + 8] = f2bf(x1 * c + x0 * sn);

  float y0 = bfu(kf[base + j]), y1 = bfu(kf[base + j + 8]);
  float r0 = y0 * c - y1 * sn;
  float r1 = y1 * c + y0 * sn;
  kf[base + j]     = f2bf(r0);
  kf[base + j + 8] = f2bf(r1);

  size_t ko = (size_t)bs * (H_ * DR_) + h * DR_;
  krot_out[ko + j]      = r0;
  krot_out[ko + j + 8]  = r1;
  krot_out[ko + 16 + j] = bfu(kf[base + 16 + j]);
  krot_out[ko + 24 + j] = bfu(kf[base + 24 + j]);
}

// ---------- flash attention: paired q-tiles, dbuf K/V, 1 barrier/tile ----------
// vt layout: [h*128+d][b*2048+s], s interleaved per 32-block (phys 2k,2k+1 =
// logical k, k+16) to match cvt_pk-packed P. Grid 512; XCD x owns 4 bh ->
// its K/V working set (4MB) fits the XCD-private L2.
#define KST 136
#define VST 40
#define PST 40
__global__ __launch_bounds__(256) void attn_kernel(
    const unsigned short* __restrict__ qf, const unsigned short* __restrict__ kf,
    const unsigned short* __restrict__ vt, unsigned short* __restrict__ ao) {
  __shared__ unsigned short Ks[2][32 * KST];
  __shared__ unsigned short Vs[2][128 * VST];
  __shared__ unsigned short Ps[4][16 * PST];

  int bid0 = blockIdx.x;            // 0..511
  int xcd  = bid0 & 7;              // HW XCD (round-robin dispatch)
  int idx  = bid0 >> 3;             // 0..63 within XCD
  int bh   = xcd * 4 + (idx >> 4);  // 4 bh per XCD
  int jp   = idx & 15;              // pair: q-tiles jp and 31-jp (uniform work)
  int h    = bh & 15;
  int b    = bh >> 4;

  int tid  = threadIdx.x;
  int wave = tid >> 6;
  int lane = tid & 63;
  int l16  = lane & 15;
  int quad = lane >> 4;

  // staging maps
  int srow  = tid >> 3;          // K rows 0..31
  int sd0   = (tid & 7) * 16;    // K d-offset
  int vrow  = tid >> 1;          // Vt rows 0..127 (d)
  int vhalf = (tid & 1) * 16;    // Vt k-offset

  const unsigned short* kbase =
      kf + ((size_t)(b * S_ + srow)) * 2048 + h * 128 + sd0;
  const unsigned short* vbase =
      vt + ((size_t)(h * 128 + vrow)) * 4096 + b * 2048 + vhalf;

#define ACOMPUTE() do {                                                       \
    int kt0 = t << 5;                                                         \
    if (kt0 <= qg_hi) {                                                       \
      const unsigned short* Kc = Ks[cur];                                     \
      const unsigned short* Vc = Vs[cur];                                     \
      floatx4 s0v = {0.f,0.f,0.f,0.f}, s1v = {0.f,0.f,0.f,0.f};               \
      __builtin_amdgcn_s_setprio(1);                                          \
      _Pragma("unroll")                                                       \
      for (int c = 0; c < 4; c++) {                                           \
        short8 kfr = *(const short8*)&Kc[l16 * KST + c * 32 + quad * 8];      \
        s0v = __builtin_amdgcn_mfma_f32_16x16x32_bf16(qfrag[c], kfr, s0v, 0, 0, 0); \
      }                                                                       \
      _Pragma("unroll")                                                       \
      for (int c = 0; c < 4; c++) {                                           \
        short8 kfr = *(const short8*)&Kc[(16 + l16) * KST + c * 32 + quad * 8]; \
        s1v = __builtin_amdgcn_mfma_f32_16x16x32_bf16(qfrag[c], kfr, s1v, 0, 0, 0); \
      }                                                                       \
      __builtin_amdgcn_s_setprio(0);                                          \
      unsigned short* P = Ps[wave];                                           \
      bool diag = (kt0 + 31 > qg_lo);                                         \
      _Pragma("unroll")                                                       \
      for (int r = 0; r < 4; r++) {                                           \
        float p0 = exp2f(fminf(s0v[r], 80.f));                                \
        float p1 = exp2f(fminf(s1v[r], 80.f));                                \
        if (diag) {                                                           \
          int q_r = qg_lo + quad * 4 + r;                                     \
          if (kt0 + l16 > q_r)      p0 = 0.f;                                 \
          if (kt0 + 16 + l16 > q_r) p1 = 0.f;                                 \
        }                                                                     \
        unsigned pk;                                                          \
        asm("v_cvt_pk_bf16_f32 %0, %1, %2" : "=v"(pk) : "v"(p0), "v"(p1));    \
        *(unsigned*)&P[(quad * 4 + r) * PST + 2 * l16] = pk;                  \
        lpart[r] += p0 + p1;                                                  \
      }                                                                       \
      short8 pfrag = *(const short8*)&P[l16 * PST + quad * 8];                \
      __builtin_amdgcn_s_setprio(1);                                          \
      _Pragma("unroll")                                                       \
      for (int dt = 0; dt < 8; dt++) {                                        \
        short8 vfr = *(const short8*)&Vc[(dt * 16 + l16) * VST + quad * 8];   \
        Oacc[dt] = __builtin_amdgcn_mfma_f32_16x16x32_bf16(pfrag, vfr, Oacc[dt], 0, 0, 0); \
      }                                                                       \
      __builtin_amdgcn_s_setprio(0);                                          \
    } } while (0)

// One k-tile: write next buf from regs (loaded 2 iters ago), issue t+2 loads,
// compute current buf, single barrier.
#define ABODY(W0, W1, W2, W3, L0, L1, L2, L3) do {                            \
    unsigned short* kdw = &Ks[cur ^ 1][srow * KST + sd0];                     \
    unsigned short* vdw = &Vs[cur ^ 1][vrow * VST + vhalf];                   \
    *(short8*)kdw = W0; *(short8*)(kdw + 8) = W1;                             \
    *(short8*)vdw = W2; *(short8*)(vdw + 8) = W3;                             \
    { int tf = (t + 2 < nkt) ? t + 2 : nkt - 1;                               \
      const unsigned short* ksrc = kbase + (size_t)tf * 65536;                \
      const unsigned short* vsrc = vbase + tf * 32;                           \
      L0 = *(const short8*)ksrc; L1 = *(const short8*)(ksrc + 8);             \
      L2 = *(const short8*)vsrc; L3 = *(const short8*)(vsrc + 8); }           \
    ACOMPUTE();                                                               \
    __syncthreads();                                                          \
    cur ^= 1; } while (0)

  for (int half = 0; half < 2; half++) {
    int jj = half ? (31 - jp) : jp;
    int q0 = jj << 6;

    // Q fragments: pre-scaled by qscale*log2e in the projection epilogue.
    int qrow = q0 + wave * 16 + l16;
    const unsigned short* qbase =
        qf + ((size_t)(b * S_ + qrow)) * 2048 + h * 128 + quad * 8;
    short8 qfrag[4];
#pragma unroll
    for (int c = 0; c < 4; c++) qfrag[c] = *(const short8*)(qbase + c * 32);

    floatx4 Oacc[8];
#pragma unroll
    for (int dt = 0; dt < 8; dt++) Oacc[dt] = (floatx4){0.f, 0.f, 0.f, 0.f};
    float lpart[4] = {0.f, 0.f, 0.f, 0.f};

    int qg_lo = q0 + wave * 16;
    int qg_hi = qg_lo + 15;
    int nkt = 2 * jj + 2;

    // prologue: stage tile 0 into buf0; preload tile 1 into reg set A
    short8 rA0, rA1, rA2, rA3, rB0, rB1, rB2, rB3;
    rA0 = *(const short8*)kbase;       rA1 = *(const short8*)(kbase + 8);
    rA2 = *(const short8*)vbase;       rA3 = *(const short8*)(vbase + 8);
    {
      unsigned short* kdw = &Ks[0][srow * KST + sd0];
      unsigned short* vdw = &Vs[0][vrow * VST + vhalf];
      *(short8*)kdw = rA0; *(short8*)(kdw + 8) = rA1;
      *(short8*)vdw = rA2; *(short8*)(vdw + 8) = rA3;
    }
    {
      const unsigned short* ksrc = kbase + 65536;  // tile 1 (nkt >= 2 always)
      const unsigned short* vsrc = vbase + 32;
      rA0 = *(const short8*)ksrc; rA1 = *(const short8*)(ksrc + 8);
      rA2 = *(const short8*)vsrc; rA3 = *(const short8*)(vsrc + 8);
    }
    __syncthreads();

    int cur = 0, t = 0;
    while (true) {
      ABODY(rA0, rA1, rA2, rA3, rB0, rB1, rB2, rB3);
      if (++t >= nkt) break;
      ABODY(rB0, rB1, rB2, rB3, rA0, rA1, rA2, rA3);
      if (++t >= nkt) break;
    }

    // epilogue: one l-reduction per q-tile
    float linv[4];
#pragma unroll
    for (int r = 0; r < 4; r++) {
      float ls = lpart[r];
#pragma unroll
      for (int sh = 1; sh < 16; sh <<= 1) ls += __shfl_xor(ls, sh);
      linv[r] = 1.0f / ls;
    }
    int qg = q0 + wave * 16 + quad * 4;
#pragma unroll
    for (int r = 0; r < 4; r++) {
      unsigned short* dst = ao + ((size_t)(b * S_ + qg + r)) * 2048 + h * 128 + l16;
#pragma unroll
      for (int dt = 0; dt < 8; dt++) dst[dt * 16] = f2bf(Oacc[dt][r] * linv[r]);
    }
  }
#undef ABODY
#undef ACOMPUTE
}

static inline Seg mkseg(float* oF, unsigned short* oB, const float* bias,
                        const float* biasM, int orow, int chunk, int gstride,
                        int obase, int nstart, int ileave, float oscale) {
  Seg s;
  s.outF = oF; s.outB = oB; s.bias = bias; s.biasM = biasM;
  s.orow = orow; s.chunk = chunk; s.gstride = gstride;
  s.obase = obase; s.nstart = nstart; s.ileave = ileave; s.oscale = oscale;
  return s;
}
static inline Seg segnone() {
  return mkseg(nullptr, nullptr, nullptr, nullptr, 1, 1, 1, 0, 0x7fffffff, 0, 1.f);
}
static inline TEnt mktent(const float* W, unsigned short* Wt, int K, int N,
                          int ntiles, int nx) {
  TEnt e;
  e.W = W; e.Wt = Wt; e.K = K; e.N = N; e.ntiles = ntiles; e.nx = nx;
  return e;
}

extern "C" void kernel_launch(void* const* d_in, const int* in_sizes, int n_in,
                              void* d_out, int out_size, void* d_ws, size_t ws_size,
                              hipStream_t stream) {
  const float* h     = (const float*)d_in[0];
  const float* W_dkv = (const float*)d_in[1];
  const float* b_dkv = (const float*)d_in[2];
  const float* W_dq  = (const float*)d_in[3];
  const float* b_dq  = (const float*)d_in[4];
  const float* W_uk  = (const float*)d_in[5];
  const float* b_uk  = (const float*)d_in[6];
  const float* W_uv  = (const float*)d_in[7];
  const float* b_uv  = (const float*)d_in[8];
  const float* W_uq  = (const float*)d_in[9];
  const float* b_uq  = (const float*)d_in[10];
  const float* W_qr  = (const float*)d_in[11];
  const float* b_qr  = (const float*)d_in[12];
  const float* W_kr  = (const float*)d_in[13];
  const float* b_kr  = (const float*)d_in[14];
  const float* W_out = (const float*)d_in[15];
  const float* b_out = (const float*)d_in[16];

  float* out      = (float*)d_out;
  float* out_ckv  = out + (size_t)M_ * E_;
  float* out_krot = out_ckv + (size_t)M_ * C_;

  unsigned short* w16 = (unsigned short*)d_ws;
  unsigned short* h_bf   = w16;                 //  8,388,608
  unsigned short* q_bf   = w16 + 8388608;       //  8,388,608
  unsigned short* k_bf   = w16 + 16777216;      //  8,388,608
  unsigned short* vt_bf  = w16 + 25165824;      //  8,388,608  (V^T, s interleaved)
  unsigned short* ao_bf  = w16 + 33554432;      //  8,388,608
  unsigned short* ckv_bf = w16 + 41943040;      //  2,097,152
  unsigned short* cq_bf  = w16 + 44040192;      //  2,097,152
  // fused weight 1: rows [0,512)=W_dkv^T, [512,1024)=W_dq^T, [1024,1536)=W_kr^T
  unsigned short* Wt_dkv = w16 + 46137344;      //  1,048,576
  unsigned short* Wt_dq  = w16 + 47185920;      //  1,048,576 (= WtF1 + 512*2048)
  unsigned short* Wt_kr  = w16 + 48234496;      //  1,048,576 (= WtF1 + 1024*2048)
  unsigned short* Wt_uk  = w16 + 49283072;      //    786,432
  unsigned short* Wt_uv  = w16 + 50069504;      //  1,048,576
  // fused weight 2: rows [0,1536)=W_uq^T, [1536,2048)=W_qr^T
  unsigned short* Wt_uq  = w16 + 51118080;      //    786,432
  unsigned short* Wt_qr  = w16 + 51904512;      //    262,144 (= WtF2 + 1536*512)
  unsigned short* Wt_out = w16 + 52166656;      //  4,194,304

  dim3 blk(256);
  const float qscale = 0.08838834764831845f * LOG2E;  // 1/sqrt(128)*log2(e)

  // conversions
  f2bf_kernel<<<8192, blk, 0, stream>>>(h, h_bf);

  // all 8 weight transposes, one launch (9984 tiles)
  TTab tab;
  tab.e[0] = mktent(W_dkv, Wt_dkv, E_, C_,       1024, 16);
  tab.e[1] = mktent(W_dq,  Wt_dq,  E_, C_,       1024, 16);
  tab.e[2] = mktent(W_kr,  Wt_kr,  E_, H_ * DR_, 1024, 16);
  tab.e[3] = mktent(W_uk,  Wt_uk,  C_, H_ * SP_,  768, 48);
  tab.e[4] = mktent(W_uv,  Wt_uv,  C_, H_ * DH_, 1024, 64);
  tab.e[5] = mktent(W_uq,  Wt_uq,  C_, H_ * SP_,  768, 48);
  tab.e[6] = mktent(W_qr,  Wt_qr,  C_, H_ * DR_,  256, 16);
  tab.e[7] = mktent(W_out, Wt_out, E_, E_,       4096, 64);
  transpose_all_kernel<<<9984, blk, 0, stream>>>(tab);

  // fused projection 1: [c_kv | c_q | k_rot_pre] = h @ [W_dkv|W_dq|W_kr]
  mfma_gemm<<<dim3(1536 / 128, M_ / 128), blk, 0, stream>>>(
      h_bf, Wt_dkv,
      mkseg(out_ckv, ckv_bf, b_dkv, nullptr, C_, C_, C_, 0, 0, 0, 1.f),
      mkseg(nullptr, cq_bf,  b_dq,  nullptr, C_, C_, C_, 0, 512, 0, 1.f),
      mkseg(nullptr, k_bf,   b_kr,  nullptr, 2048, DR_, DH_, SP_, 1024, 0, 1.f),
      E_);
  // k = c_kv @ W_uk (head-remapped into k_bf cols [0,96) per head)
  mfma_gemm<<<dim3((H_ * SP_) / 128, M_ / 128), blk, 0, stream>>>(
      ckv_bf, Wt_uk,
      mkseg(nullptr, k_bf, b_uk, nullptr, 2048, SP_, DH_, 0, 0, 0, 1.f),
      segnone(), segnone(), C_);
  // V^T = W_uv^T @ c_kv^T (swapped operands); s-columns interleaved per
  // 32-block to match cvt_pk-packed P in attention. biasM = b_uv (row axis).
  mfma_gemm<<<dim3(M_ / 128, (H_ * DH_) / 128), blk, 0, stream>>>(
      Wt_uv, ckv_bf,
      mkseg(nullptr, vt_bf, nullptr, b_uv, M_, M_, M_, 0, 0, 1, 1.f),
      segnone(), segnone(), C_);
  // fused projection 2: [q_base | q_rot_pre] = c_q @ [W_uq|W_qr], pre-scaled
  mfma_gemm<<<dim3(2048 / 128, M_ / 128), blk, 0, stream>>>(
      cq_bf, Wt_uq,
      mkseg(nullptr, q_bf, b_uq, nullptr, 2048, SP_, DH_, 0, 0, 0, qscale),
      mkseg(nullptr, q_bf, b_qr, nullptr, 2048, DR_, DH_, SP_, 1536, 0, qscale),
      segnone(), C_);

  rope_kernel<<<(M_ * H_ * 8) / 256, blk, 0, stream>>>(q_bf, k_bf, out_krot);
  // paired-q flash attention: grid = B*H*16 = 512, XCD-swizzled in-kernel
  attn_kernel<<<B_ * H_ * 16, blk, 0, stream>>>(q_bf, k_bf, vt_bf, ao_bf);

  // out = ao @ W_out + b  (fp32 -> d_out region 0)
  mfma_gemm<<<dim3(E_ / 128, M_ / 128), blk, 0, stream>>>(
      ao_bf, Wt_out,
      mkseg(out, nullptr, b_out, nullptr, E_, E_, E_, 0, 0, 0, 1.f),
      segnone(), segnone(), E_);
}

// Round 5
// 368.476 us; speedup vs baseline: 1.5866x; 1.0198x over previous
//
#include <hip/hip_runtime.h>
#include <hip/hip_bf16.h>

// MLA forward. Storage fp32 in/out; internal pipeline bf16 MFMA, fp32 accum.
// R5 changes vs R4 (376us):
//  - attn: merged-pair k-loop with KVBLK=64. One loop over the hi tile's
//    64-row K/V chunks; the paired lo tile (subset k-range) consumes the
//    SAME staged chunks -> staging 33->24.5 chunks avg, barriers 66->24.5.
//    K/V LDS XOR-swizzled (slot ^= row&7 on 16B slots), pad-free: all
//    staging writes and fragment reads hit the uniform 8-lanes-per-4-bank
//    minimum. LDS 73KB -> 2 blocks/CU. Keeps reg-prefetch(t+2) 1-barrier
//    body, setprio, cvt_pk P-pack, interleaved V^T, pre-scaled Q.
//  - GEMMs / transposes / rope unchanged from R4.
#define B_   2
#define S_   2048
#define E_   2048
#define H_   16
#define DH_  128
#define DR_  32
#define SP_  96
#define C_   512
#define M_   (B_ * S_)   // 4096 rows

#define LOG2E 1.4426950408889634f

typedef __attribute__((ext_vector_type(8))) short short8;
typedef __attribute__((ext_vector_type(4))) float floatx4;

__device__ __forceinline__ float bfu(unsigned short u) {
  return __uint_as_float((unsigned)u << 16);
}
__device__ __forceinline__ unsigned short f2bf(float f) {
  unsigned u = __float_as_uint(f);
  return (unsigned short)((u + 0x7fff + ((u >> 16) & 1)) >> 16);  // RNE
}

// async global->LDS, 16B per lane. LDS dest: wave-uniform base + lane*16.
__device__ __forceinline__ void gload16(const void* g, void* l) {
  __builtin_amdgcn_global_load_lds(
      (const __attribute__((address_space(1))) void*)g,
      (__attribute__((address_space(3))) void*)l, 16, 0, 0);
}

// ---------- fp32 -> bf16 bulk convert (for h) ----------
__global__ __launch_bounds__(256) void f2bf_kernel(
    const float* __restrict__ src, unsigned short* __restrict__ dst) {
  size_t i = ((size_t)blockIdx.x * 256 + threadIdx.x) * 4;
  float4 v = *(const float4*)(src + i);
  ushort4 w;
  w.x = f2bf(v.x); w.y = f2bf(v.y); w.z = f2bf(v.z); w.w = f2bf(v.w);
  *(ushort4*)(dst + i) = w;
}

// ---------- all 8 weight transposes in ONE launch ----------
struct TEnt { const float* W; unsigned short* Wt; int K, N, ntiles, nx; };
struct TTab { TEnt e[8]; };

__global__ __launch_bounds__(256) void transpose_all_kernel(TTab tab) {
  __shared__ unsigned short T[32][33];
  int rem = blockIdx.x;
  const float* W = nullptr; unsigned short* Wt = nullptr;
  int K = 0, N = 0, nx = 1;
  bool done = false;
#pragma unroll
  for (int j = 0; j < 8; j++) {   // constant-index select (stays in SGPRs)
    if (!done) {
      if (rem < tab.e[j].ntiles) {
        W = tab.e[j].W; Wt = tab.e[j].Wt;
        K = tab.e[j].K; N = tab.e[j].N; nx = tab.e[j].nx;
        done = true;
      } else {
        rem -= tab.e[j].ntiles;
      }
    }
  }
  int n0 = (rem % nx) * 32, k0 = (rem / nx) * 32;
  int t = threadIdx.x, lane = t & 31, grp = t >> 5;
#pragma unroll
  for (int p = 0; p < 4; p++) {
    int k = p * 8 + grp;
    T[lane][k] = f2bf(W[(size_t)(k0 + k) * N + n0 + lane]);
  }
  __syncthreads();
#pragma unroll
  for (int p = 0; p < 4; p++) {
    int n = p * 8 + grp;
    Wt[(size_t)(n0 + n) * K + k0 + lane] = T[n][lane];
  }
}

// ---------- bf16 MFMA GEMM, multi-segment epilogue, 2-phase pipeline ----------
struct Seg {
  float* outF;
  unsigned short* outB;
  const float* bias;    // indexed by n_local
  const float* biasM;   // indexed by m (overrides bias)
  int orow, chunk, gstride, obase, nstart, ileave;
  float oscale;
};

__global__ __launch_bounds__(256) void mfma_gemm(
    const unsigned short* __restrict__ A, const unsigned short* __restrict__ Wt,
    Seg s0, Seg s1, Seg s2, int K) {
  __shared__ unsigned short As0[128 * 32];
  __shared__ unsigned short Bs0[128 * 32];
  __shared__ unsigned short As1[128 * 32];
  __shared__ unsigned short Bs1[128 * 32];
  int tid = threadIdx.x;
  int lane = tid & 63, wave = tid >> 6;
  int l16 = lane & 15, quad = lane >> 4;

  // XCD swizzle (bijective; nwg % 8 == 0 at every call site)
  int gx = gridDim.x;
  int nwg = gx * gridDim.y;
  int flat = blockIdx.y * gx + blockIdx.x;
  int w = (flat & 7) * (nwg >> 3) + (flat >> 3);
  int by = w / gx, bx = w - by * gx;
  int bm = by * 128, bn = bx * 128;
  int wm = (wave & 1) * 64, wn = (wave >> 1) * 64;

  floatx4 acc[4][4];
#pragma unroll
  for (int mt = 0; mt < 4; mt++)
#pragma unroll
    for (int nt = 0; nt < 4; nt++) acc[mt][nt] = (floatx4){0.f, 0.f, 0.f, 0.f};

  // staging: 8 chunks of 1KB per operand; wave w owns chunks 2w,2w+1.
  int c0 = wave * 2, c1 = c0 + 1;
  int srow = lane >> 2, scol = (lane & 3) * 8;
  const unsigned short* Ag0 = A + (size_t)(bm + c0 * 16 + srow) * K + scol;
  const unsigned short* Ag1 = A + (size_t)(bm + c1 * 16 + srow) * K + scol;
  const unsigned short* Bg0 = Wt + (size_t)(bn + c0 * 16 + srow) * K + scol;
  const unsigned short* Bg1 = Wt + (size_t)(bn + c1 * 16 + srow) * K + scol;

#define GSTAGE(kk, Asb, Bsb) do {            \
    gload16(Ag0 + (kk), &Asb[c0 * 512]);     \
    gload16(Ag1 + (kk), &Asb[c1 * 512]);     \
    gload16(Bg0 + (kk), &Bsb[c0 * 512]);     \
    gload16(Bg1 + (kk), &Bsb[c1 * 512]); } while (0)

#define GCOMPUTE(Asb, Bsb) do {                                            \
    short8 af[4], bfv[4];                                                  \
    _Pragma("unroll")                                                      \
    for (int mt = 0; mt < 4; mt++)                                         \
      af[mt] = *(const short8*)&Asb[(wm + mt * 16 + l16) * 32 + quad * 8]; \
    _Pragma("unroll")                                                      \
    for (int nt = 0; nt < 4; nt++)                                         \
      bfv[nt] = *(const short8*)&Bsb[(wn + nt * 16 + l16) * 32 + quad * 8];\
    _Pragma("unroll")                                                      \
    for (int mt = 0; mt < 4; mt++)                                         \
      _Pragma("unroll")                                                    \
      for (int nt = 0; nt < 4; nt++)                                       \
        acc[mt][nt] = __builtin_amdgcn_mfma_f32_16x16x32_bf16(             \
            af[mt], bfv[nt], acc[mt][nt], 0, 0, 0); } while (0)

  GSTAGE(0, As0, Bs0);
  __syncthreads();
  for (int k0 = 0; k0 < K; k0 += 64) {
    GSTAGE(k0 + 32, As1, Bs1);
    GCOMPUTE(As0, Bs0);
    __syncthreads();
    if (k0 + 64 < K) GSTAGE(k0 + 64, As0, Bs0);
    GCOMPUTE(As1, Bs1);
    __syncthreads();
  }
#undef GSTAGE
#undef GCOMPUTE

  Seg sg = (bn >= s2.nstart) ? s2 : ((bn >= s1.nstart) ? s1 : s0);

  // C/D layout: D[row=quad*4+r][col=l16]
#pragma unroll
  for (int mt = 0; mt < 4; mt++) {
    int m0 = bm + wm + mt * 16 + quad * 4;
    float bm4[4] = {0.f, 0.f, 0.f, 0.f};
    if (sg.biasM) {
#pragma unroll
      for (int r = 0; r < 4; r++) bm4[r] = sg.biasM[m0 + r];
    }
#pragma unroll
    for (int nt = 0; nt < 4; nt++) {
      int n = bn + wn + nt * 16 + l16;
      int nl = n - sg.nstart;
      float bv = sg.biasM ? 0.f : sg.bias[nl];
      int ncol = sg.obase + (nl / sg.chunk) * sg.gstride + (nl % sg.chunk);
      if (sg.ileave)
        ncol = (ncol & ~31) | ((ncol & 15) << 1) | ((ncol >> 4) & 1);
#pragma unroll
      for (int r = 0; r < 4; r++) {
        float val = (acc[mt][nt][r] + (sg.biasM ? bm4[r] : bv)) * sg.oscale;
        size_t idx = (size_t)(m0 + r) * sg.orow + ncol;
        if (sg.outF) sg.outF[idx] = val;
        if (sg.outB) sg.outB[idx] = f2bf(val);
      }
    }
  }
}

// ---------- RoPE on bf16 q/k; fp32 k_rot to d_out ----------
__global__ __launch_bounds__(256) void rope_kernel(
    unsigned short* __restrict__ qf, unsigned short* __restrict__ kf,
    float* __restrict__ krot_out) {
  int idx = blockIdx.x * 256 + threadIdx.x;
  int j  = idx & 7;
  int h  = (idx >> 3) & (H_ - 1);
  int bs = idx >> 7;
  if (bs >= M_) return;
  int s = bs & (S_ - 1);
  float t = (float)s / 40.0f;
  float ang = t * exp2f(-1.6609640474436813f * (float)j);  // 10000^(-j/8)
  float c = cosf(ang), sn = sinf(ang);

  size_t base = (size_t)bs * 2048 + h * 128 + 96;
  float x0 = bfu(qf[base + j]), x1 = bfu(qf[base + j + 8]);
  qf[base + j]     = f2bf(x0 * c - x1 * sn);
  qf[base + j + 8] = f2bf(x1 * c + x0 * sn);

  float y0 = bfu(kf[base + j]), y1 = bfu(kf[base + j + 8]);
  float r0 = y0 * c - y1 * sn;
  float r1 = y1 * c + y0 * sn;
  kf[base + j]     = f2bf(r0);
  kf[base + j + 8] = f2bf(r1);

  size_t ko = (size_t)bs * (H_ * DR_) + h * DR_;
  krot_out[ko + j]      = r0;
  krot_out[ko + j + 8]  = r1;
  krot_out[ko + 16 + j] = bfu(kf[base + 16 + j]);
  krot_out[ko + 24 + j] = bfu(kf[base + 24 + j]);
}

// ---------- flash attention: merged pair, KVBLK=64, swizzled LDS ----------
// vt layout: [h*128+d][b*2048+s], s interleaved per 32-block (matches the
// cvt_pk-packed P). Grid 512; XCD x owns 4 bh -> K/V fits its private L2.
// Block handles q-tiles jp (lo) and 31-jp (hi); ONE k-loop over the hi
// range; lo consumes the same staged chunks while t <= jj_lo.
// LDS (pad-free, XOR-swizzled 16B slots): K[2][64][128d], V[2][128d][64k].
#define PST 72
__global__ __launch_bounds__(256, 2) void attn_kernel(
    const unsigned short* __restrict__ qf, const unsigned short* __restrict__ kf,
    const unsigned short* __restrict__ vt, unsigned short* __restrict__ ao) {
  __shared__ unsigned short Ks[2][64 * 128];   // row=k (256B), 16 slots
  __shared__ unsigned short Vs[2][128 * 64];   // row=d (128B), 8 slots
  __shared__ unsigned short Ps[4][16 * PST];

  int bid0 = blockIdx.x;            // 0..511
  int xcd  = bid0 & 7;
  int idx  = bid0 >> 3;
  int bh   = xcd * 4 + (idx >> 4);
  int jp   = idx & 15;
  int h    = bh & 15;
  int b    = bh >> 4;
  int jjh  = 31 - jp;               // hi q-tile
  int jjl  = jp;                    // lo q-tile
  int q0h  = jjh << 6, q0l = jjl << 6;
  int nchunks = jjh + 1;            // 64-k chunks (17..32)

  int tid  = threadIdx.x;
  int wave = tid >> 6;
  int lane = tid & 63;
  int l16  = lane & 15;
  int quad = lane >> 4;
  int x7   = l16 & 7;

  // ---- staging maps (per thread: 4x16B K + 4x16B V per chunk) ----
  int krow = tid >> 2;              // 0..63
  int kst  = (tid & 3) * 4;         // starting 16B slot of 16
  int vrow = tid >> 1;              // 0..127
  int vst  = (tid & 1) * 4;         // starting 16B slot of 8
  const unsigned short* kg =
      kf + ((size_t)(b * S_ + krow)) * 2048 + h * 128 + kst * 8;
  const unsigned short* vg =
      vt + ((size_t)(h * 128 + vrow)) * 4096 + b * 2048 + vst * 8;
  // swizzled LDS write offsets (shorts)
  int kwl[4], vwl[4];
#pragma unroll
  for (int i = 0; i < 4; i++) {
    kwl[i] = krow * 128 + (((kst + i) ^ (krow & 7)) * 8);
    vwl[i] = vrow * 64  + (((vst + i) ^ (vrow & 7)) * 8);
  }

  // ---- Q fragments for both sides (pre-scaled in projection epilogue) ----
  short8 qfh[4], qfl[4];
  {
    const unsigned short* qb =
        qf + ((size_t)(b * S_ + q0h + wave * 16 + l16)) * 2048 + h * 128 + quad * 8;
#pragma unroll
    for (int c = 0; c < 4; c++) qfh[c] = *(const short8*)(qb + c * 32);
  }
  {
    const unsigned short* qb =
        qf + ((size_t)(b * S_ + q0l + wave * 16 + l16)) * 2048 + h * 128 + quad * 8;
#pragma unroll
    for (int c = 0; c < 4; c++) qfl[c] = *(const short8*)(qb + c * 32);
  }

  floatx4 OaccH[8], OaccL[8];
#pragma unroll
  for (int dt = 0; dt < 8; dt++) {
    OaccH[dt] = (floatx4){0.f, 0.f, 0.f, 0.f};
    OaccL[dt] = (floatx4){0.f, 0.f, 0.f, 0.f};
  }
  float lpH[4] = {0.f, 0.f, 0.f, 0.f};
  float lpL[4] = {0.f, 0.f, 0.f, 0.f};
  int qgh = q0h + wave * 16;        // base q row of this wave, hi side
  int qgl = q0l + wave * 16;

  // one side's compute vs staged chunk t in buf `cur`
#define SCOMPUTE(QF, OC, LP, QG, DIAG) do {                                   \
    const unsigned short* Kc = Ks[cur];                                       \
    const unsigned short* Vc = Vs[cur];                                       \
    floatx4 sv[4];                                                            \
    _Pragma("unroll")                                                         \
    for (int nt = 0; nt < 4; nt++) sv[nt] = (floatx4){0.f, 0.f, 0.f, 0.f};    \
    __builtin_amdgcn_s_setprio(1);                                            \
    _Pragma("unroll")                                                         \
    for (int nt = 0; nt < 4; nt++)                                            \
      _Pragma("unroll")                                                       \
      for (int c = 0; c < 4; c++) {                                           \
        short8 kfr = *(const short8*)&Kc[(nt * 16 + l16) * 128 +              \
                                         ((4 * c + quad) ^ x7) * 8];          \
        sv[nt] = __builtin_amdgcn_mfma_f32_16x16x32_bf16(QF[c], kfr, sv[nt],  \
                                                         0, 0, 0);            \
      }                                                                       \
    __builtin_amdgcn_s_setprio(0);                                            \
    unsigned short* P = Ps[wave];                                             \
    _Pragma("unroll")                                                         \
    for (int ks = 0; ks < 2; ks++)                                            \
      _Pragma("unroll")                                                       \
      for (int r = 0; r < 4; r++) {                                           \
        float p0 = exp2f(fminf(sv[2 * ks][r], 80.f));                         \
        float p1 = exp2f(fminf(sv[2 * ks + 1][r], 80.f));                     \
        if (DIAG) {                                                           \
          int q_r = QG + quad * 4 + r;                                        \
          int kc0 = kt0 + ks * 32 + l16;                                      \
          if (kc0 > q_r)      p0 = 0.f;                                       \
          if (kc0 + 16 > q_r) p1 = 0.f;                                       \
        }                                                                     \
        unsigned pk;                                                          \
        asm("v_cvt_pk_bf16_f32 %0, %1, %2" : "=v"(pk) : "v"(p0), "v"(p1));    \
        *(unsigned*)&P[(quad * 4 + r) * PST + ks * 32 + 2 * l16] = pk;        \
        LP[r] += p0 + p1;                                                     \
      }                                                                       \
    short8 pf0 = *(const short8*)&P[l16 * PST + quad * 8];                    \
    short8 pf1 = *(const short8*)&P[l16 * PST + 32 + quad * 8];               \
    __builtin_amdgcn_s_setprio(1);                                            \
    _Pragma("unroll")                                                         \
    for (int dt = 0; dt < 8; dt++) {                                          \
      short8 vf0 = *(const short8*)&Vc[(dt * 16 + l16) * 64 +                 \
                                       ((quad) ^ x7) * 8];                    \
      OC[dt] = __builtin_amdgcn_mfma_f32_16x16x32_bf16(pf0, vf0, OC[dt],      \
                                                       0, 0, 0);              \
      short8 vf1 = *(const short8*)&Vc[(dt * 16 + l16) * 64 +                 \
                                       ((4 + quad) ^ x7) * 8];                \
      OC[dt] = __builtin_amdgcn_mfma_f32_16x16x32_bf16(pf1, vf1, OC[dt],      \
                                                       0, 0, 0);              \
    }                                                                         \
    __builtin_amdgcn_s_setprio(0);                                            \
  } while (0)

  // ---- prologue: chunk 0 -> buf0; chunk 1 -> regs ----
  short8 kr[4], vr[4];
#pragma unroll
  for (int i = 0; i < 4; i++) {
    kr[i] = *(const short8*)(kg + i * 8);
    vr[i] = *(const short8*)(vg + i * 8);
  }
#pragma unroll
  for (int i = 0; i < 4; i++) {
    *(short8*)&Ks[0][kwl[i]] = kr[i];
    *(short8*)&Vs[0][vwl[i]] = vr[i];
  }
#pragma unroll
  for (int i = 0; i < 4; i++) {       // chunk 1 (nchunks >= 17)
    kr[i] = *(const short8*)(kg + 131072 + i * 8);
    vr[i] = *(const short8*)(vg + 64 + i * 8);
  }
  __syncthreads();

  int cur = 0;
  for (int t = 0; t < nchunks; t++) {
    // write chunk t+1 from regs into the other buffer
#pragma unroll
    for (int i = 0; i < 4; i++) {
      *(short8*)&Ks[cur ^ 1][kwl[i]] = kr[i];
      *(short8*)&Vs[cur ^ 1][vwl[i]] = vr[i];
    }
    // prefetch chunk t+2 (clamped)
    {
      int tf = (t + 2 < nchunks) ? t + 2 : nchunks - 1;
      const unsigned short* ksrc = kg + (size_t)tf * 131072;
      const unsigned short* vsrc = vg + tf * 64;
#pragma unroll
      for (int i = 0; i < 4; i++) {
        kr[i] = *(const short8*)(ksrc + i * 8);
        vr[i] = *(const short8*)(vsrc + i * 8);
      }
    }
    int kt0 = t << 6;
    SCOMPUTE(qfh, OaccH, lpH, qgh, (t == jjh));
    if (t <= jjl) SCOMPUTE(qfl, OaccL, lpL, qgl, (t == jjl));
    __syncthreads();
    cur ^= 1;
  }
#undef SCOMPUTE

  // ---- epilogue: l-reduction + store, both sides ----
#pragma unroll
  for (int side = 0; side < 2; side++) {
    floatx4* OC = side ? OaccL : OaccH;
    float*   LP = side ? lpL : lpH;
    int qg = (side ? qgl : qgh) + quad * 4;
    float linv[4];
#pragma unroll
    for (int r = 0; r < 4; r++) {
      float ls = LP[r];
#pragma unroll
      for (int sh = 1; sh < 16; sh <<= 1) ls += __shfl_xor(ls, sh);
      linv[r] = 1.0f / ls;
    }
#pragma unroll
    for (int r = 0; r < 4; r++) {
      unsigned short* dst =
          ao + ((size_t)(b * S_ + qg + r)) * 2048 + h * 128 + l16;
#pragma unroll
      for (int dt = 0; dt < 8; dt++) dst[dt * 16] = f2bf(OC[dt][r] * linv[r]);
    }
  }
}

static inline Seg mkseg(float* oF, unsigned short* oB, const float* bias,
                        const float* biasM, int orow, int chunk, int gstride,
                        int obase, int nstart, int ileave, float oscale) {
  Seg s;
  s.outF = oF; s.outB = oB; s.bias = bias; s.biasM = biasM;
  s.orow = orow; s.chunk = chunk; s.gstride = gstride;
  s.obase = obase; s.nstart = nstart; s.ileave = ileave; s.oscale = oscale;
  return s;
}
static inline Seg segnone() {
  return mkseg(nullptr, nullptr, nullptr, nullptr, 1, 1, 1, 0, 0x7fffffff, 0, 1.f);
}
static inline TEnt mktent(const float* W, unsigned short* Wt, int K, int N,
                          int ntiles, int nx) {
  TEnt e;
  e.W = W; e.Wt = Wt; e.K = K; e.N = N; e.ntiles = ntiles; e.nx = nx;
  return e;
}

extern "C" void kernel_launch(void* const* d_in, const int* in_sizes, int n_in,
                              void* d_out, int out_size, void* d_ws, size_t ws_size,
                              hipStream_t stream) {
  const float* h     = (const float*)d_in[0];
  const float* W_dkv = (const float*)d_in[1];
  const float* b_dkv = (const float*)d_in[2];
  const float* W_dq  = (const float*)d_in[3];
  const float* b_dq  = (const float*)d_in[4];
  const float* W_uk  = (const float*)d_in[5];
  const float* b_uk  = (const float*)d_in[6];
  const float* W_uv  = (const float*)d_in[7];
  const float* b_uv  = (const float*)d_in[8];
  const float* W_uq  = (const float*)d_in[9];
  const float* b_uq  = (const float*)d_in[10];
  const float* W_qr  = (const float*)d_in[11];
  const float* b_qr  = (const float*)d_in[12];
  const float* W_kr  = (const float*)d_in[13];
  const float* b_kr  = (const float*)d_in[14];
  const float* W_out = (const float*)d_in[15];
  const float* b_out = (const float*)d_in[16];

  float* out      = (float*)d_out;
  float* out_ckv  = out + (size_t)M_ * E_;
  float* out_krot = out_ckv + (size_t)M_ * C_;

  unsigned short* w16 = (unsigned short*)d_ws;
  unsigned short* h_bf   = w16;                 //  8,388,608
  unsigned short* q_bf   = w16 + 8388608;       //  8,388,608
  unsigned short* k_bf   = w16 + 16777216;      //  8,388,608
  unsigned short* vt_bf  = w16 + 25165824;      //  8,388,608  (V^T, s interleaved)
  unsigned short* ao_bf  = w16 + 33554432;      //  8,388,608
  unsigned short* ckv_bf = w16 + 41943040;      //  2,097,152
  unsigned short* cq_bf  = w16 + 44040192;      //  2,097,152
  // fused weight 1: rows [0,512)=W_dkv^T, [512,1024)=W_dq^T, [1024,1536)=W_kr^T
  unsigned short* Wt_dkv = w16 + 46137344;      //  1,048,576
  unsigned short* Wt_dq  = w16 + 47185920;      //  1,048,576 (= WtF1 + 512*2048)
  unsigned short* Wt_kr  = w16 + 48234496;      //  1,048,576 (= WtF1 + 1024*2048)
  unsigned short* Wt_uk  = w16 + 49283072;      //    786,432
  unsigned short* Wt_uv  = w16 + 50069504;      //  1,048,576
  // fused weight 2: rows [0,1536)=W_uq^T, [1536,2048)=W_qr^T
  unsigned short* Wt_uq  = w16 + 51118080;      //    786,432
  unsigned short* Wt_qr  = w16 + 51904512;      //    262,144 (= WtF2 + 1536*512)
  unsigned short* Wt_out = w16 + 52166656;      //  4,194,304

  dim3 blk(256);
  const float qscale = 0.08838834764831845f * LOG2E;  // 1/sqrt(128)*log2(e)

  // conversions
  f2bf_kernel<<<8192, blk, 0, stream>>>(h, h_bf);

  // all 8 weight transposes, one launch (9984 tiles)
  TTab tab;
  tab.e[0] = mktent(W_dkv, Wt_dkv, E_, C_,       1024, 16);
  tab.e[1] = mktent(W_dq,  Wt_dq,  E_, C_,       1024, 16);
  tab.e[2] = mktent(W_kr,  Wt_kr,  E_, H_ * DR_, 1024, 16);
  tab.e[3] = mktent(W_uk,  Wt_uk,  C_, H_ * SP_,  768, 48);
  tab.e[4] = mktent(W_uv,  Wt_uv,  C_, H_ * DH_, 1024, 64);
  tab.e[5] = mktent(W_uq,  Wt_uq,  C_, H_ * SP_,  768, 48);
  tab.e[6] = mktent(W_qr,  Wt_qr,  C_, H_ * DR_,  256, 16);
  tab.e[7] = mktent(W_out, Wt_out, E_, E_,       4096, 64);
  transpose_all_kernel<<<9984, blk, 0, stream>>>(tab);

  // fused projection 1: [c_kv | c_q | k_rot_pre] = h @ [W_dkv|W_dq|W_kr]
  mfma_gemm<<<dim3(1536 / 128, M_ / 128), blk, 0, stream>>>(
      h_bf, Wt_dkv,
      mkseg(out_ckv, ckv_bf, b_dkv, nullptr, C_, C_, C_, 0, 0, 0, 1.f),
      mkseg(nullptr, cq_bf,  b_dq,  nullptr, C_, C_, C_, 0, 512, 0, 1.f),
      mkseg(nullptr, k_bf,   b_kr,  nullptr, 2048, DR_, DH_, SP_, 1024, 0, 1.f),
      E_);
  // k = c_kv @ W_uk (head-remapped into k_bf cols [0,96) per head)
  mfma_gemm<<<dim3((H_ * SP_) / 128, M_ / 128), blk, 0, stream>>>(
      ckv_bf, Wt_uk,
      mkseg(nullptr, k_bf, b_uk, nullptr, 2048, SP_, DH_, 0, 0, 0, 1.f),
      segnone(), segnone(), C_);
  // V^T = W_uv^T @ c_kv^T (swapped operands); s-columns interleaved per
  // 32-block to match cvt_pk-packed P in attention. biasM = b_uv (row axis).
  mfma_gemm<<<dim3(M_ / 128, (H_ * DH_) / 128), blk, 0, stream>>>(
      Wt_uv, ckv_bf,
      mkseg(nullptr, vt_bf, nullptr, b_uv, M_, M_, M_, 0, 0, 1, 1.f),
      segnone(), segnone(), C_);
  // fused projection 2: [q_base | q_rot_pre] = c_q @ [W_uq|W_qr], pre-scaled
  mfma_gemm<<<dim3(2048 / 128, M_ / 128), blk, 0, stream>>>(
      cq_bf, Wt_uq,
      mkseg(nullptr, q_bf, b_uq, nullptr, 2048, SP_, DH_, 0, 0, 0, qscale),
      mkseg(nullptr, q_bf, b_qr, nullptr, 2048, DR_, DH_, SP_, 1536, 0, qscale),
      segnone(), C_);

  rope_kernel<<<(M_ * H_ * 8) / 256, blk, 0, stream>>>(q_bf, k_bf, out_krot);
  // merged-pair flash attention: grid = B*H*16 = 512, XCD-swizzled in-kernel
  attn_kernel<<<B_ * H_ * 16, blk, 0, stream>>>(q_bf, k_bf, vt_bf, ao_bf);

  // out = ao @ W_out + b  (fp32 -> d_out region 0)
  mfma_gemm<<<dim3(E_ / 128, M_ / 128), blk, 0, stream>>>(
      ao_bf, Wt_out,
      mkseg(out, nullptr, b_out, nullptr, E_, E_, E_, 0, 0, 0, 1.f),
      segnone(), segnone(), E_);
}